// Round 1
// baseline (2112.444 us; speedup 1.0000x reference)
//
#include <hip/hip_runtime.h>
#include <hip/hip_bf16.h>

#define NNODES 50000
#define NEDGES 600000
#define NGRAPHS 128
#define EMB 128
#define NLAYERS 5
#define BN_EPS 1e-5f

// ---------------- edge preprocessing: deg, wsum, S = segsum(edge_attr*w) ----
__global__ __launch_bounds__(256) void edge_pre(const int* __restrict__ ei,
                                                const float* __restrict__ eattr,
                                                const float* __restrict__ ew,
                                                int* __restrict__ deg,
                                                float* __restrict__ wsum,
                                                float* __restrict__ S) {
    int e = blockIdx.x * 256 + threadIdx.x;
    if (e >= NEDGES) return;
    int dst = ei[NEDGES + e];
    float w = ew[e];
    atomicAdd(&deg[dst], 1);
    atomicAdd(&wsum[dst], w);
#pragma unroll
    for (int j = 0; j < 11; j++)
        atomicAdd(&S[dst * 11 + j], eattr[e * 11 + j] * w);
}

// ---------------- single-block exclusive scan of deg -> rowptr, cursor ------
__global__ __launch_bounds__(1024) void scan_kernel(const int* __restrict__ deg,
                                                    int* __restrict__ rowptr,
                                                    int* __restrict__ cursor) {
    __shared__ int temp[1024];
    __shared__ int carry;
    int tid = threadIdx.x;
    if (tid == 0) carry = 0;
    __syncthreads();
    for (int base = 0; base < NNODES; base += 1024) {
        int i = base + tid;
        int v = (i < NNODES) ? deg[i] : 0;
        temp[tid] = v;
        __syncthreads();
        for (int off = 1; off < 1024; off <<= 1) {
            int t = 0;
            if (tid >= off) t = temp[tid - off];
            __syncthreads();
            temp[tid] += t;
            __syncthreads();
        }
        int excl = temp[tid] - v;
        int base_carry = carry;
        if (i < NNODES) {
            rowptr[i] = base_carry + excl;
            cursor[i] = base_carry + excl;
        }
        __syncthreads();
        if (tid == 0) carry += temp[1023];
        __syncthreads();
    }
    if (tid == 0) rowptr[NNODES] = carry;
}

// ---------------- fill CSR ---------------------------------------------------
__global__ __launch_bounds__(256) void edge_fill(const int* __restrict__ ei,
                                                 const float* __restrict__ ew,
                                                 int* __restrict__ cursor,
                                                 int* __restrict__ csr_src,
                                                 float* __restrict__ csr_w) {
    int e = blockIdx.x * 256 + threadIdx.x;
    if (e >= NEDGES) return;
    int src = ei[e];
    int dst = ei[NEDGES + e];
    int pos = atomicAdd(&cursor[dst], 1);
    csr_src[pos] = src;
    csr_w[pos] = ew[e];
}

// ---------------- encoder: h0 = x @ W_atom + b_atom  (K=48) ------------------
__global__ __launch_bounds__(256) void enc_atom(const float* __restrict__ X,
                                                const float* __restrict__ W,
                                                const float* __restrict__ b,
                                                float* __restrict__ H) {
    __shared__ float as[32 * 48];
    int row0 = blockIdx.x * 32;
    int t = threadIdx.x;
    for (int i = t; i < 32 * 48; i += 256) {
        int r = i / 48, c = i - r * 48;
        int gr = row0 + r;
        as[i] = (gr < NNODES) ? X[gr * 48 + c] : 0.f;
    }
    __syncthreads();
    int c = t & 127, rh = t >> 7;
    float acc[16];
#pragma unroll
    for (int i = 0; i < 16; i++) acc[i] = 0.f;
    for (int k = 0; k < 48; k++) {
        float w = W[k * 128 + c];
#pragma unroll
        for (int i = 0; i < 16; i++) acc[i] += as[(rh * 16 + i) * 48 + k] * w;
    }
    float bb = b[c];
    for (int i = 0; i < 16; i++) {
        int gr = row0 + rh * 16 + i;
        if (gr < NNODES) H[gr * 128 + c] = acc[i] + bb;
    }
}

// ---------------- eagg = S @ W_bond + b_bond * wsum  (K=11) ------------------
__global__ __launch_bounds__(256) void enc_bond(const float* __restrict__ S,
                                                const float* __restrict__ W,
                                                const float* __restrict__ b,
                                                const float* __restrict__ wsum,
                                                float* __restrict__ EA) {
    __shared__ float as[32 * 11];
    __shared__ float wss[32];
    int row0 = blockIdx.x * 32;
    int t = threadIdx.x;
    for (int i = t; i < 32 * 11; i += 256) {
        int r = i / 11, c = i - r * 11;
        int gr = row0 + r;
        as[i] = (gr < NNODES) ? S[gr * 11 + c] : 0.f;
    }
    if (t < 32) wss[t] = (row0 + t < NNODES) ? wsum[row0 + t] : 0.f;
    __syncthreads();
    int c = t & 127, rh = t >> 7;
    float acc[16];
#pragma unroll
    for (int i = 0; i < 16; i++) acc[i] = 0.f;
    for (int k = 0; k < 11; k++) {
        float w = W[k * 128 + c];
#pragma unroll
        for (int i = 0; i < 16; i++) acc[i] += as[(rh * 16 + i) * 11 + k] * w;
    }
    float bb = b[c];
    for (int i = 0; i < 16; i++) {
        int gr = row0 + rh * 16 + i;
        if (gr < NNODES) EA[gr * 128 + c] = acc[i] + bb * wss[rh * 16 + i];
    }
}

// ---------------- per-layer aggregation --------------------------------------
__global__ __launch_bounds__(256) void agg_kernel(const float* __restrict__ H,
                                                  const float* __restrict__ eagg,
                                                  const int* __restrict__ rowptr,
                                                  const int* __restrict__ csr_src,
                                                  const float* __restrict__ csr_w,
                                                  const int* __restrict__ deg,
                                                  float* __restrict__ agg) {
    int t = threadIdx.x;
    int c = t & 127, half = t >> 7;
    int node = blockIdx.x * 2 + half;
    if (node >= NNODES) return;
    int start = rowptr[node], end = rowptr[node + 1];
    float s = 0.f;
    for (int e = start; e < end; e++) {
        int src = csr_src[e];
        float w = csr_w[e];
        s += H[src * 128 + c] * w;
    }
    float denom = fmaxf((float)deg[node], 1.f);
    agg[node * 128 + c] = (s + eagg[node * 128 + c]) / denom;
}

// ---------------- hnew = agg@Wl + h@Wr + bl ----------------------------------
__global__ __launch_bounds__(256) void layer_gemm(const float* __restrict__ A1,
                                                  const float* __restrict__ A2,
                                                  const float* __restrict__ B1,
                                                  const float* __restrict__ B2,
                                                  const float* __restrict__ bias,
                                                  float* __restrict__ C) {
    __shared__ float a1s[32 * 128];
    __shared__ float a2s[32 * 128];
    int row0 = blockIdx.x * 32;
    int t = threadIdx.x;
    for (int i = t; i < 32 * 128; i += 256) {
        int r = i >> 7, c = i & 127;
        int gr = row0 + r;
        a1s[i] = (gr < NNODES) ? A1[gr * 128 + c] : 0.f;
        a2s[i] = (gr < NNODES) ? A2[gr * 128 + c] : 0.f;
    }
    __syncthreads();
    int c = t & 127, rh = t >> 7;
    float acc[16];
#pragma unroll
    for (int i = 0; i < 16; i++) acc[i] = 0.f;
    for (int k = 0; k < 128; k++) {
        float w1 = B1[k * 128 + c];
        float w2 = B2[k * 128 + c];
#pragma unroll
        for (int i = 0; i < 16; i++) {
            int r = rh * 16 + i;
            acc[i] += a1s[r * 128 + k] * w1 + a2s[r * 128 + k] * w2;
        }
    }
    float bb = bias[c];
    for (int i = 0; i < 16; i++) {
        int gr = row0 + rh * 16 + i;
        if (gr < NNODES) C[gr * 128 + c] = acc[i] + bb;
    }
}

// ---------------- BN statistics ----------------------------------------------
__global__ __launch_bounds__(256) void bn_stat(const float* __restrict__ H,
                                               float* __restrict__ stat) {
    int t = threadIdx.x;
    int c = t & 127, half = t >> 7;
    float s = 0.f, q = 0.f;
    for (int r = blockIdx.x * 2 + half; r < NNODES; r += gridDim.x * 2) {
        float v = H[r * 128 + c];
        s += v;
        q += v * v;
    }
    __shared__ float ls[256], lq[256];
    ls[t] = s;
    lq[t] = q;
    __syncthreads();
    if (half == 0) {
        atomicAdd(&stat[c], ls[c] + ls[c + 128]);
        atomicAdd(&stat[128 + c], lq[c] + lq[c + 128]);
    }
}

__global__ __launch_bounds__(128) void bn_coef(const float* __restrict__ stat,
                                               const float* __restrict__ gamma,
                                               const float* __restrict__ beta,
                                               float* __restrict__ coef) {
    int c = threadIdx.x;
    const float invM = 1.f / (float)NNODES;
    float mu = stat[c] * invM;
    float var = stat[128 + c] * invM - mu * mu;
    float inv = rsqrtf(var + BN_EPS);
    float sc = gamma[c] * inv;
    coef[c] = sc;
    coef[128 + c] = beta[c] - mu * sc;
}

// ---------------- BN apply + ReLU + xpool accumulation -----------------------
__global__ __launch_bounds__(256) void bn_apply(const float* __restrict__ Hin,
                                                float* __restrict__ Hout,
                                                const float* __restrict__ coef,
                                                const int* __restrict__ batch,
                                                float* __restrict__ pool,
                                                int layer, int relu) {
    int t = threadIdx.x;
    int c = t & 127, half = t >> 7;
    float sc = coef[c], sh = coef[128 + c];
    int row0 = blockIdx.x * 128;
    float accp = 0.f;
    int curg = -1;
    for (int rr = half; rr < 128; rr += 2) {
        int r = row0 + rr;
        if (r >= NNODES) break;
        float v = Hin[r * 128 + c] * sc + sh;
        if (relu) v = fmaxf(v, 0.f);
        Hout[r * 128 + c] = v;
        int g = batch[r];
        if (g != curg) {
            if (curg >= 0) atomicAdd(&pool[curg * 640 + layer * 128 + c], accp);
            curg = g;
            accp = 0.f;
        }
        accp += v;
    }
    if (curg >= 0) atomicAdd(&pool[curg * 640 + layer * 128 + c], accp);
}

extern "C" void kernel_launch(void* const* d_in, const int* in_sizes, int n_in,
                              void* d_out, int out_size, void* d_ws, size_t ws_size,
                              hipStream_t stream) {
    const int* batch = (const int*)d_in[0];
    const float* x = (const float*)d_in[1];
    const int* edge_index = (const int*)d_in[2];
    const float* edge_attr = (const float*)d_in[3];
    const float* edge_weight = (const float*)d_in[4];
    const float* W_atom = (const float*)d_in[5];
    const float* b_atom = (const float*)d_in[6];
    const float* W_bond = (const float*)d_in[7];
    const float* b_bond = (const float*)d_in[8];
    const float* Wl = (const float*)d_in[9];
    const float* bl = (const float*)d_in[10];
    const float* Wr = (const float*)d_in[11];
    const float* gamma = (const float*)d_in[12];
    const float* beta = (const float*)d_in[13];
    float* out = (float*)d_out;

    // ---- workspace layout ----
    char* ws = (char*)d_ws;
    size_t off = 0;
    auto alloc = [&](size_t bytes) -> void* {
        void* p = ws + off;
        off += (bytes + 255) & ~(size_t)255;
        return p;
    };
    float* hA   = (float*)alloc((size_t)NNODES * 128 * 4);
    float* hB   = (float*)alloc((size_t)NNODES * 128 * 4);
    float* agg  = (float*)alloc((size_t)NNODES * 128 * 4);
    float* eagg = (float*)alloc((size_t)NNODES * 128 * 4);
    float* csr_w = (float*)alloc((size_t)NEDGES * 4);
    int* csr_src = (int*)alloc((size_t)NEDGES * 4);
    int* rowptr = (int*)alloc((size_t)(NNODES + 1) * 4);
    int* cursor = (int*)alloc((size_t)NNODES * 4);
    int* deg = (int*)alloc((size_t)NNODES * 4);
    float* wsum = (float*)alloc((size_t)NNODES * 4);
    float* S = (float*)alloc((size_t)NNODES * 11 * 4);
    float* stat = (float*)alloc(NLAYERS * 256 * 4);
    float* coef = (float*)alloc(256 * 4);

    // ---- zero-init accumulation buffers ----
    hipMemsetAsync(out, 0, (size_t)NGRAPHS * 640 * 4, stream);       // xpool region
    hipMemsetAsync(deg, 0, (size_t)NNODES * 4, stream);
    hipMemsetAsync(wsum, 0, (size_t)NNODES * 4, stream);
    hipMemsetAsync(S, 0, (size_t)NNODES * 11 * 4, stream);
    hipMemsetAsync(stat, 0, NLAYERS * 256 * 4, stream);

    // ---- preprocessing ----
    edge_pre<<<(NEDGES + 255) / 256, 256, 0, stream>>>(edge_index, edge_attr, edge_weight,
                                                       deg, wsum, S);
    scan_kernel<<<1, 1024, 0, stream>>>(deg, rowptr, cursor);
    edge_fill<<<(NEDGES + 255) / 256, 256, 0, stream>>>(edge_index, edge_weight, cursor,
                                                        csr_src, csr_w);
    enc_atom<<<(NNODES + 31) / 32, 256, 0, stream>>>(x, W_atom, b_atom, hA);
    enc_bond<<<(NNODES + 31) / 32, 256, 0, stream>>>(S, W_bond, b_bond, wsum, eagg);

    // ---- layers ----
    float* hcur = hA;
    for (int i = 0; i < NLAYERS; i++) {
        agg_kernel<<<(NNODES + 1) / 2, 256, 0, stream>>>(hcur, eagg, rowptr, csr_src,
                                                         csr_w, deg, agg);
        layer_gemm<<<(NNODES + 31) / 32, 256, 0, stream>>>(agg, hcur,
                                                           Wl + (size_t)i * 128 * 128,
                                                           Wr + (size_t)i * 128 * 128,
                                                           bl + i * 128, hB);
        bn_stat<<<512, 256, 0, stream>>>(hB, stat + i * 256);
        bn_coef<<<1, 128, 0, stream>>>(stat + i * 256, gamma + i * 128, beta + i * 128, coef);
        float* dsth = (i == NLAYERS - 1) ? (out + (size_t)NGRAPHS * 640) : hcur;
        bn_apply<<<(NNODES + 127) / 128, 256, 0, stream>>>(hB, dsth, coef, batch, out, i,
                                                           (i < NLAYERS - 1) ? 1 : 0);
        hcur = dsth;
    }
}

// Round 2
// 1232.209 us; speedup vs baseline: 1.7144x; 1.7144x over previous
//
#include <hip/hip_runtime.h>
#include <hip/hip_bf16.h>

#define NNODES 50000
#define NEDGES 600000
#define NGRAPHS 128
#define EMB 128
#define NLAYERS 5
#define BN_EPS 1e-5f

// ---------------- deg histogram (int atomics only) ---------------------------
__global__ __launch_bounds__(256) void deg_kernel(const int* __restrict__ ei,
                                                  int* __restrict__ deg) {
    int e = blockIdx.x * 256 + threadIdx.x;
    if (e >= NEDGES) return;
    atomicAdd(&deg[ei[NEDGES + e]], 1);
}

// ---------------- single-block scan: serial chunks + block scan --------------
__global__ __launch_bounds__(1024) void scan_kernel(const int* __restrict__ deg,
                                                    int* __restrict__ rowptr,
                                                    int* __restrict__ cursor) {
    __shared__ int part[1024];
    int t = threadIdx.x;
    const int CHUNK = 49;  // 1024*49 = 50176 >= NNODES
    int begin = t * CHUNK;
    int end = begin + CHUNK;
    if (end > NNODES) end = NNODES;
    int s = 0;
    for (int i = begin; i < end; i++) s += deg[i];
    part[t] = s;
    __syncthreads();
    for (int off = 1; off < 1024; off <<= 1) {
        int v = (t >= off) ? part[t - off] : 0;
        __syncthreads();
        part[t] += v;
        __syncthreads();
    }
    int run = part[t] - s;  // exclusive prefix of this chunk
    for (int i = begin; i < end; i++) {
        rowptr[i] = run;
        cursor[i] = run;
        run += deg[i];
    }
    if (t == 1023) rowptr[NNODES] = part[1023];
}

// ---------------- fill CSR (src, w, eid) -------------------------------------
__global__ __launch_bounds__(256) void edge_fill(const int* __restrict__ ei,
                                                 const float* __restrict__ ew,
                                                 int* __restrict__ cursor,
                                                 int* __restrict__ csr_src,
                                                 float* __restrict__ csr_w,
                                                 int* __restrict__ csr_eid) {
    int e = blockIdx.x * 256 + threadIdx.x;
    if (e >= NEDGES) return;
    int src = ei[e];
    int dst = ei[NEDGES + e];
    int pos = atomicAdd(&cursor[dst], 1);
    csr_src[pos] = src;
    csr_w[pos] = ew[e];
    csr_eid[pos] = e;
}

// ---------------- S[n,11], wsum[n] via CSR segmented sum (no atomics) --------
__global__ __launch_bounds__(256) void node_S(const float* __restrict__ eattr,
                                              const int* __restrict__ rowptr,
                                              const int* __restrict__ csr_eid,
                                              const float* __restrict__ csr_w,
                                              float* __restrict__ S,
                                              float* __restrict__ wsum) {
    int t = threadIdx.x;
    int j = t & 15, grp = t >> 4;  // 16 lanes per node
    int node = blockIdx.x * 16 + grp;
    if (node >= NNODES) return;
    int b = rowptr[node], e = rowptr[node + 1];
    float s = 0.f;
    for (int p = b; p < e; p++) {
        int eid = csr_eid[p];
        float w = csr_w[p];
        if (j < 11) s += eattr[eid * 11 + j] * w;
        else if (j == 11) s += w;
    }
    if (j < 11) S[node * 11 + j] = s;
    else if (j == 11) wsum[node] = s;
}

// ---------------- encoder: h0 = x @ W_atom + b_atom  (K=48) ------------------
__global__ __launch_bounds__(256) void enc_atom(const float* __restrict__ X,
                                                const float* __restrict__ W,
                                                const float* __restrict__ b,
                                                float* __restrict__ H) {
    __shared__ float as[32 * 48];
    int row0 = blockIdx.x * 32;
    int t = threadIdx.x;
    for (int i = t; i < 32 * 48; i += 256) {
        int r = i / 48, c = i - r * 48;
        int gr = row0 + r;
        as[i] = (gr < NNODES) ? X[gr * 48 + c] : 0.f;
    }
    __syncthreads();
    int c = t & 127, rh = t >> 7;
    float acc[16];
#pragma unroll
    for (int i = 0; i < 16; i++) acc[i] = 0.f;
    for (int k = 0; k < 48; k++) {
        float w = W[k * 128 + c];
#pragma unroll
        for (int i = 0; i < 16; i++) acc[i] += as[(rh * 16 + i) * 48 + k] * w;
    }
    float bb = b[c];
    for (int i = 0; i < 16; i++) {
        int gr = row0 + rh * 16 + i;
        if (gr < NNODES) H[gr * 128 + c] = acc[i] + bb;
    }
}

// ---------------- eagg = S @ W_bond + b_bond * wsum  (K=11) ------------------
__global__ __launch_bounds__(256) void enc_bond(const float* __restrict__ S,
                                                const float* __restrict__ W,
                                                const float* __restrict__ b,
                                                const float* __restrict__ wsum,
                                                float* __restrict__ EA) {
    __shared__ float as[32 * 11];
    __shared__ float wss[32];
    int row0 = blockIdx.x * 32;
    int t = threadIdx.x;
    for (int i = t; i < 32 * 11; i += 256) {
        int r = i / 11, c = i - r * 11;
        int gr = row0 + r;
        as[i] = (gr < NNODES) ? S[gr * 11 + c] : 0.f;
    }
    if (t < 32) wss[t] = (row0 + t < NNODES) ? wsum[row0 + t] : 0.f;
    __syncthreads();
    int c = t & 127, rh = t >> 7;
    float acc[16];
#pragma unroll
    for (int i = 0; i < 16; i++) acc[i] = 0.f;
    for (int k = 0; k < 11; k++) {
        float w = W[k * 128 + c];
#pragma unroll
        for (int i = 0; i < 16; i++) acc[i] += as[(rh * 16 + i) * 11 + k] * w;
    }
    float bb = b[c];
    for (int i = 0; i < 16; i++) {
        int gr = row0 + rh * 16 + i;
        if (gr < NNODES) EA[gr * 128 + c] = acc[i] + bb * wss[rh * 16 + i];
    }
}

// ---------------- per-layer aggregation (float4 per thread) ------------------
__global__ __launch_bounds__(256) void agg_kernel(const float* __restrict__ H,
                                                  const float* __restrict__ eagg,
                                                  const int* __restrict__ rowptr,
                                                  const int* __restrict__ csr_src,
                                                  const float* __restrict__ csr_w,
                                                  float* __restrict__ agg) {
    int t = threadIdx.x;
    int lane = t & 31, grp = t >> 5;
    int c4 = lane * 4;
    int node = blockIdx.x * 8 + grp;
    if (node >= NNODES) return;
    int b = rowptr[node], e = rowptr[node + 1];
    float4 s = {0.f, 0.f, 0.f, 0.f};
    for (int p = b; p < e; p++) {
        int src = csr_src[p];
        float w = csr_w[p];
        float4 h = *(const float4*)&H[src * 128 + c4];
        s.x += h.x * w;
        s.y += h.y * w;
        s.z += h.z * w;
        s.w += h.w * w;
    }
    float denom = fmaxf((float)(e - b), 1.f);
    float inv = 1.f / denom;
    float4 ea = *(const float4*)&eagg[node * 128 + c4];
    float4 o;
    o.x = (s.x + ea.x) * inv;
    o.y = (s.y + ea.y) * inv;
    o.z = (s.z + ea.z) * inv;
    o.w = (s.w + ea.w) * inv;
    *(float4*)&agg[node * 128 + c4] = o;
}

// ---------------- hnew = agg@Wl + h@Wr + bl, fused BN partial stats ----------
__global__ __launch_bounds__(256) void layer_gemm(const float* __restrict__ A1,
                                                  const float* __restrict__ A2,
                                                  const float* __restrict__ B1,
                                                  const float* __restrict__ B2,
                                                  const float* __restrict__ bias,
                                                  float* __restrict__ C,
                                                  float* __restrict__ stat) {
    __shared__ float a1s[32 * 128];
    __shared__ float a2s[32 * 128];
    int row0 = blockIdx.x * 32;
    int t = threadIdx.x;
    for (int i = t * 4; i < 32 * 128; i += 256 * 4) {
        int r = i >> 7, c = i & 127;
        int gr = row0 + r;
        if (gr < NNODES) {
            *(float4*)&a1s[i] = *(const float4*)&A1[gr * 128 + c];
            *(float4*)&a2s[i] = *(const float4*)&A2[gr * 128 + c];
        } else {
            float4 z = {0.f, 0.f, 0.f, 0.f};
            *(float4*)&a1s[i] = z;
            *(float4*)&a2s[i] = z;
        }
    }
    __syncthreads();
    int c = t & 127, rh = t >> 7;
    float acc[16];
#pragma unroll
    for (int i = 0; i < 16; i++) acc[i] = 0.f;
    const float* a1p = &a1s[rh * 16 * 128];
    const float* a2p = &a2s[rh * 16 * 128];
    for (int k = 0; k < 128; k += 4) {
        float w10 = B1[k * 128 + c];
        float w11 = B1[(k + 1) * 128 + c];
        float w12 = B1[(k + 2) * 128 + c];
        float w13 = B1[(k + 3) * 128 + c];
        float w20 = B2[k * 128 + c];
        float w21 = B2[(k + 1) * 128 + c];
        float w22 = B2[(k + 2) * 128 + c];
        float w23 = B2[(k + 3) * 128 + c];
#pragma unroll
        for (int i = 0; i < 16; i++) {
            float4 a1 = *(const float4*)&a1p[i * 128 + k];
            float4 a2 = *(const float4*)&a2p[i * 128 + k];
            acc[i] += a1.x * w10 + a1.y * w11 + a1.z * w12 + a1.w * w13 +
                      a2.x * w20 + a2.y * w21 + a2.z * w22 + a2.w * w23;
        }
    }
    float bb = bias[c];
    float s = 0.f, q = 0.f;
#pragma unroll
    for (int i = 0; i < 16; i++) {
        int gr = row0 + rh * 16 + i;
        if (gr < NNODES) {
            float v = acc[i] + bb;
            C[gr * 128 + c] = v;
            s += v;
            q += v * v;
        }
    }
    __syncthreads();
    a1s[t] = s;
    a2s[t] = q;
    __syncthreads();
    if (rh == 0) {
        atomicAdd(&stat[c], a1s[c] + a1s[128 + c]);
        atomicAdd(&stat[128 + c], a2s[c] + a2s[128 + c]);
    }
}

__global__ __launch_bounds__(128) void bn_coef(const float* __restrict__ stat,
                                               const float* __restrict__ gamma,
                                               const float* __restrict__ beta,
                                               float* __restrict__ coef) {
    int c = threadIdx.x;
    const float invM = 1.f / (float)NNODES;
    float mu = stat[c] * invM;
    float var = stat[128 + c] * invM - mu * mu;
    float inv = rsqrtf(var + BN_EPS);
    float sc = gamma[c] * inv;
    coef[c] = sc;
    coef[128 + c] = beta[c] - mu * sc;
}

// ---------------- BN apply + ReLU + xpool accumulation (float4) --------------
__global__ __launch_bounds__(256) void bn_apply(const float* __restrict__ Hin,
                                                float* __restrict__ Hout,
                                                const float* __restrict__ coef,
                                                const int* __restrict__ batch,
                                                float* __restrict__ pool,
                                                int layer, int relu) {
    int t = threadIdx.x;
    int lane = t & 31, grp = t >> 5;
    int c4 = lane * 4;
    float4 sc = *(const float4*)&coef[c4];
    float4 sh = *(const float4*)&coef[128 + c4];
    int row0 = blockIdx.x * 256;
    float4 accp = {0.f, 0.f, 0.f, 0.f};
    int curg = -1;
    float* pbase = pool + layer * 128 + c4;
    for (int rr = grp; rr < 256; rr += 8) {
        int r = row0 + rr;
        if (r >= NNODES) break;
        float4 v = *(const float4*)&Hin[r * 128 + c4];
        v.x = v.x * sc.x + sh.x;
        v.y = v.y * sc.y + sh.y;
        v.z = v.z * sc.z + sh.z;
        v.w = v.w * sc.w + sh.w;
        if (relu) {
            v.x = fmaxf(v.x, 0.f);
            v.y = fmaxf(v.y, 0.f);
            v.z = fmaxf(v.z, 0.f);
            v.w = fmaxf(v.w, 0.f);
        }
        *(float4*)&Hout[r * 128 + c4] = v;
        int g = batch[r];
        if (g != curg) {
            if (curg >= 0) {
                float* p = pbase + curg * 640;
                atomicAdd(p + 0, accp.x);
                atomicAdd(p + 1, accp.y);
                atomicAdd(p + 2, accp.z);
                atomicAdd(p + 3, accp.w);
            }
            curg = g;
            accp.x = accp.y = accp.z = accp.w = 0.f;
        }
        accp.x += v.x;
        accp.y += v.y;
        accp.z += v.z;
        accp.w += v.w;
    }
    if (curg >= 0) {
        float* p = pbase + curg * 640;
        atomicAdd(p + 0, accp.x);
        atomicAdd(p + 1, accp.y);
        atomicAdd(p + 2, accp.z);
        atomicAdd(p + 3, accp.w);
    }
}

extern "C" void kernel_launch(void* const* d_in, const int* in_sizes, int n_in,
                              void* d_out, int out_size, void* d_ws, size_t ws_size,
                              hipStream_t stream) {
    const int* batch = (const int*)d_in[0];
    const float* x = (const float*)d_in[1];
    const int* edge_index = (const int*)d_in[2];
    const float* edge_attr = (const float*)d_in[3];
    const float* edge_weight = (const float*)d_in[4];
    const float* W_atom = (const float*)d_in[5];
    const float* b_atom = (const float*)d_in[6];
    const float* W_bond = (const float*)d_in[7];
    const float* b_bond = (const float*)d_in[8];
    const float* Wl = (const float*)d_in[9];
    const float* bl = (const float*)d_in[10];
    const float* Wr = (const float*)d_in[11];
    const float* gamma = (const float*)d_in[12];
    const float* beta = (const float*)d_in[13];
    float* out = (float*)d_out;

    // ---- workspace layout ----
    char* ws = (char*)d_ws;
    size_t off = 0;
    auto alloc = [&](size_t bytes) -> void* {
        void* p = ws + off;
        off += (bytes + 255) & ~(size_t)255;
        return p;
    };
    float* hA = (float*)alloc((size_t)NNODES * 128 * 4);
    float* hB = (float*)alloc((size_t)NNODES * 128 * 4);
    float* agg = (float*)alloc((size_t)NNODES * 128 * 4);
    float* eagg = (float*)alloc((size_t)NNODES * 128 * 4);
    float* csr_w = (float*)alloc((size_t)NEDGES * 4);
    int* csr_src = (int*)alloc((size_t)NEDGES * 4);
    int* csr_eid = (int*)alloc((size_t)NEDGES * 4);
    int* rowptr = (int*)alloc((size_t)(NNODES + 1) * 4);
    int* cursor = (int*)alloc((size_t)NNODES * 4);
    int* deg = (int*)alloc((size_t)NNODES * 4);
    float* wsum = (float*)alloc((size_t)NNODES * 4);
    float* S = (float*)alloc((size_t)NNODES * 11 * 4);
    float* stat = (float*)alloc(NLAYERS * 256 * 4);
    float* coef = (float*)alloc(256 * 4);

    // ---- zero-init accumulation buffers ----
    hipMemsetAsync(out, 0, (size_t)NGRAPHS * 640 * 4, stream);  // xpool region
    hipMemsetAsync(deg, 0, (size_t)NNODES * 4, stream);
    hipMemsetAsync(stat, 0, NLAYERS * 256 * 4, stream);

    // ---- preprocessing ----
    deg_kernel<<<(NEDGES + 255) / 256, 256, 0, stream>>>(edge_index, deg);
    scan_kernel<<<1, 1024, 0, stream>>>(deg, rowptr, cursor);
    edge_fill<<<(NEDGES + 255) / 256, 256, 0, stream>>>(edge_index, edge_weight, cursor,
                                                        csr_src, csr_w, csr_eid);
    node_S<<<(NNODES + 15) / 16, 256, 0, stream>>>(edge_attr, rowptr, csr_eid, csr_w,
                                                   S, wsum);
    enc_atom<<<(NNODES + 31) / 32, 256, 0, stream>>>(x, W_atom, b_atom, hA);
    enc_bond<<<(NNODES + 31) / 32, 256, 0, stream>>>(S, W_bond, b_bond, wsum, eagg);

    // ---- layers ----
    float* hcur = hA;
    for (int i = 0; i < NLAYERS; i++) {
        agg_kernel<<<(NNODES + 7) / 8, 256, 0, stream>>>(hcur, eagg, rowptr, csr_src,
                                                         csr_w, agg);
        layer_gemm<<<(NNODES + 31) / 32, 256, 0, stream>>>(agg, hcur,
                                                           Wl + (size_t)i * 128 * 128,
                                                           Wr + (size_t)i * 128 * 128,
                                                           bl + i * 128, hB,
                                                           stat + i * 256);
        bn_coef<<<1, 128, 0, stream>>>(stat + i * 256, gamma + i * 128, beta + i * 128,
                                       coef);
        float* dsth = (i == NLAYERS - 1) ? (out + (size_t)NGRAPHS * 640) : hcur;
        bn_apply<<<(NNODES + 255) / 256, 256, 0, stream>>>(hB, dsth, coef, batch, out, i,
                                                           (i < NLAYERS - 1) ? 1 : 0);
        hcur = dsth;
    }
}

// Round 3
// 1032.902 us; speedup vs baseline: 2.0452x; 1.1930x over previous
//
#include <hip/hip_runtime.h>
#include <hip/hip_bf16.h>

#define NNODES 50000
#define NEDGES 600000
#define NGRAPHS 128
#define EMB 128
#define NLAYERS 5
#define BN_EPS 1e-5f
#define SCAN_BLOCKS ((NNODES + 255) / 256)  // 196

// ---------------- deg histogram (int atomics only) ---------------------------
__global__ __launch_bounds__(256) void deg_kernel(const int* __restrict__ ei,
                                                  int* __restrict__ deg) {
    int e = blockIdx.x * 256 + threadIdx.x;
    if (e >= NEDGES) return;
    atomicAdd(&deg[ei[NEDGES + e]], 1);
}

// ---------------- multi-block scan, phase 1: local excl scan + block total ---
__global__ __launch_bounds__(256) void scan1(const int* __restrict__ deg,
                                             int* __restrict__ local_excl,
                                             int* __restrict__ part) {
    __shared__ int sh[256];
    int t = threadIdx.x;
    int i = blockIdx.x * 256 + t;
    int v = (i < NNODES) ? deg[i] : 0;
    sh[t] = v;
    __syncthreads();
    for (int off = 1; off < 256; off <<= 1) {
        int u = (t >= off) ? sh[t - off] : 0;
        __syncthreads();
        sh[t] += u;
        __syncthreads();
    }
    if (i < NNODES) local_excl[i] = sh[t] - v;
    if (t == 255) part[blockIdx.x] = sh[255];
}

// ---------------- phase 2: scan the 196 block totals -------------------------
__global__ __launch_bounds__(256) void scan2(int* __restrict__ part,
                                             int* __restrict__ blockoff,
                                             int* __restrict__ rowptr) {
    __shared__ int sh[256];
    int t = threadIdx.x;
    int v = (t < SCAN_BLOCKS) ? part[t] : 0;
    sh[t] = v;
    __syncthreads();
    for (int off = 1; off < 256; off <<= 1) {
        int u = (t >= off) ? sh[t - off] : 0;
        __syncthreads();
        sh[t] += u;
        __syncthreads();
    }
    if (t < SCAN_BLOCKS) blockoff[t] = sh[t] - v;
    if (t == 255) rowptr[NNODES] = sh[255];
}

// ---------------- phase 3: add block offsets -> rowptr, cursor ---------------
__global__ __launch_bounds__(256) void scan3(const int* __restrict__ local_excl,
                                             const int* __restrict__ blockoff,
                                             int* __restrict__ rowptr,
                                             int* __restrict__ cursor) {
    int i = blockIdx.x * 256 + threadIdx.x;
    if (i >= NNODES) return;
    int v = local_excl[i] + blockoff[blockIdx.x];
    rowptr[i] = v;
    cursor[i] = v;
}

// ---------------- fill CSR (src, w, eid) -------------------------------------
__global__ __launch_bounds__(256) void edge_fill(const int* __restrict__ ei,
                                                 const float* __restrict__ ew,
                                                 int* __restrict__ cursor,
                                                 int* __restrict__ csr_src,
                                                 float* __restrict__ csr_w,
                                                 int* __restrict__ csr_eid) {
    int e = blockIdx.x * 256 + threadIdx.x;
    if (e >= NEDGES) return;
    int src = ei[e];
    int dst = ei[NEDGES + e];
    int pos = atomicAdd(&cursor[dst], 1);
    csr_src[pos] = src;
    csr_w[pos] = ew[e];
    csr_eid[pos] = e;
}

// ---------------- S[n,11], wsum[n] via CSR segmented sum (no atomics) --------
__global__ __launch_bounds__(256) void node_S(const float* __restrict__ eattr,
                                              const int* __restrict__ rowptr,
                                              const int* __restrict__ csr_eid,
                                              const float* __restrict__ csr_w,
                                              float* __restrict__ S,
                                              float* __restrict__ wsum) {
    int t = threadIdx.x;
    int j = t & 15, grp = t >> 4;  // 16 lanes per node
    int node = blockIdx.x * 16 + grp;
    if (node >= NNODES) return;
    int b = rowptr[node], e = rowptr[node + 1];
    float s = 0.f;
    for (int p = b; p < e; p++) {
        int eid = csr_eid[p];
        float w = csr_w[p];
        if (j < 11) s += eattr[eid * 11 + j] * w;
        else if (j == 11) s += w;
    }
    if (j < 11) S[node * 11 + j] = s;
    else if (j == 11) wsum[node] = s;
}

// ---------------- encoder: h0 = x @ W_atom + b_atom  (K=48) ------------------
__global__ __launch_bounds__(256) void enc_atom(const float* __restrict__ X,
                                                const float* __restrict__ W,
                                                const float* __restrict__ b,
                                                float* __restrict__ H) {
    __shared__ float as[32 * 48];
    int row0 = blockIdx.x * 32;
    int t = threadIdx.x;
    for (int i = t; i < 32 * 48; i += 256) {
        int r = i / 48, c = i - r * 48;
        int gr = row0 + r;
        as[i] = (gr < NNODES) ? X[gr * 48 + c] : 0.f;
    }
    __syncthreads();
    int c = t & 127, rh = t >> 7;
    float acc[16];
#pragma unroll
    for (int i = 0; i < 16; i++) acc[i] = 0.f;
    for (int k = 0; k < 48; k++) {
        float w = W[k * 128 + c];
#pragma unroll
        for (int i = 0; i < 16; i++) acc[i] += as[(rh * 16 + i) * 48 + k] * w;
    }
    float bb = b[c];
    for (int i = 0; i < 16; i++) {
        int gr = row0 + rh * 16 + i;
        if (gr < NNODES) H[gr * 128 + c] = acc[i] + bb;
    }
}

// ---------------- eagg = S @ W_bond + b_bond * wsum  (K=11) ------------------
__global__ __launch_bounds__(256) void enc_bond(const float* __restrict__ S,
                                                const float* __restrict__ W,
                                                const float* __restrict__ b,
                                                const float* __restrict__ wsum,
                                                float* __restrict__ EA) {
    __shared__ float as[32 * 11];
    __shared__ float wss[32];
    int row0 = blockIdx.x * 32;
    int t = threadIdx.x;
    for (int i = t; i < 32 * 11; i += 256) {
        int r = i / 11, c = i - r * 11;
        int gr = row0 + r;
        as[i] = (gr < NNODES) ? S[gr * 11 + c] : 0.f;
    }
    if (t < 32) wss[t] = (row0 + t < NNODES) ? wsum[row0 + t] : 0.f;
    __syncthreads();
    int c = t & 127, rh = t >> 7;
    float acc[16];
#pragma unroll
    for (int i = 0; i < 16; i++) acc[i] = 0.f;
    for (int k = 0; k < 11; k++) {
        float w = W[k * 128 + c];
#pragma unroll
        for (int i = 0; i < 16; i++) acc[i] += as[(rh * 16 + i) * 11 + k] * w;
    }
    float bb = b[c];
    for (int i = 0; i < 16; i++) {
        int gr = row0 + rh * 16 + i;
        if (gr < NNODES) EA[gr * 128 + c] = acc[i] + bb * wss[rh * 16 + i];
    }
}

// ---------------- per-layer aggregation (float4, 2-edge unroll) --------------
__global__ __launch_bounds__(256) void agg_kernel(const float* __restrict__ H,
                                                  const float* __restrict__ eagg,
                                                  const int* __restrict__ rowptr,
                                                  const int* __restrict__ csr_src,
                                                  const float* __restrict__ csr_w,
                                                  float* __restrict__ agg) {
    int t = threadIdx.x;
    int lane = t & 31, grp = t >> 5;
    int c4 = lane * 4;
    int node = blockIdx.x * 8 + grp;
    if (node >= NNODES) return;
    int b = rowptr[node], e = rowptr[node + 1];
    float4 s = {0.f, 0.f, 0.f, 0.f};
    int p = b;
    for (; p + 1 < e; p += 2) {
        int s0 = csr_src[p], s1 = csr_src[p + 1];
        float w0 = csr_w[p], w1 = csr_w[p + 1];
        float4 h0 = *(const float4*)&H[s0 * 128 + c4];
        float4 h1 = *(const float4*)&H[s1 * 128 + c4];
        s.x += h0.x * w0 + h1.x * w1;
        s.y += h0.y * w0 + h1.y * w1;
        s.z += h0.z * w0 + h1.z * w1;
        s.w += h0.w * w0 + h1.w * w1;
    }
    if (p < e) {
        int s0 = csr_src[p];
        float w0 = csr_w[p];
        float4 h0 = *(const float4*)&H[s0 * 128 + c4];
        s.x += h0.x * w0;
        s.y += h0.y * w0;
        s.z += h0.z * w0;
        s.w += h0.w * w0;
    }
    float denom = fmaxf((float)(e - b), 1.f);
    float inv = 1.f / denom;
    float4 ea = *(const float4*)&eagg[node * 128 + c4];
    float4 o;
    o.x = (s.x + ea.x) * inv;
    o.y = (s.y + ea.y) * inv;
    o.z = (s.z + ea.z) * inv;
    o.w = (s.w + ea.w) * inv;
    *(float4*)&agg[node * 128 + c4] = o;
}

// ---------------- hnew = agg@Wl + h@Wr + bl, 4x4x2 register tile, fused stats
__global__ __launch_bounds__(256) void layer_gemm(const float* __restrict__ A1,
                                                  const float* __restrict__ A2,
                                                  const float* __restrict__ B1,
                                                  const float* __restrict__ B2,
                                                  const float* __restrict__ bias,
                                                  float* __restrict__ C,
                                                  float* __restrict__ stat) {
    __shared__ float a1s[32 * 128];
    __shared__ float a2s[32 * 128];
    int row0 = blockIdx.x * 32;
    int t = threadIdx.x;
    // stage A tiles (float4)
    for (int i = t * 4; i < 32 * 128; i += 256 * 4) {
        int r = i >> 7, c = i & 127;
        int gr = row0 + r;
        if (gr < NNODES) {
            *(float4*)&a1s[i] = *(const float4*)&A1[gr * 128 + c];
            *(float4*)&a2s[i] = *(const float4*)&A2[gr * 128 + c];
        } else {
            float4 z = {0.f, 0.f, 0.f, 0.f};
            *(float4*)&a1s[i] = z;
            *(float4*)&a2s[i] = z;
        }
    }
    __syncthreads();
    int c0 = (t & 31) * 4;   // 4 cols
    int rg = t >> 5;         // row group 0..7
    int r0 = rg * 4;         // 4 rows
    float acc[4][4];
#pragma unroll
    for (int rr = 0; rr < 4; rr++)
#pragma unroll
        for (int cc = 0; cc < 4; cc++) acc[rr][cc] = 0.f;

#pragma unroll 2
    for (int k = 0; k < 128; k += 4) {
        float w1v[4][4], w2v[4][4];
#pragma unroll
        for (int kk = 0; kk < 4; kk++) {
            float4 w1 = *(const float4*)&B1[(k + kk) * 128 + c0];
            float4 w2 = *(const float4*)&B2[(k + kk) * 128 + c0];
            w1v[kk][0] = w1.x; w1v[kk][1] = w1.y; w1v[kk][2] = w1.z; w1v[kk][3] = w1.w;
            w2v[kk][0] = w2.x; w2v[kk][1] = w2.y; w2v[kk][2] = w2.z; w2v[kk][3] = w2.w;
        }
#pragma unroll
        for (int rr = 0; rr < 4; rr++) {
            float4 a1 = *(const float4*)&a1s[(r0 + rr) * 128 + k];
            float4 a2 = *(const float4*)&a2s[(r0 + rr) * 128 + k];
            float a1f[4] = {a1.x, a1.y, a1.z, a1.w};
            float a2f[4] = {a2.x, a2.y, a2.z, a2.w};
#pragma unroll
            for (int kk = 0; kk < 4; kk++)
#pragma unroll
                for (int cc = 0; cc < 4; cc++)
                    acc[rr][cc] += a1f[kk] * w1v[kk][cc] + a2f[kk] * w2v[kk][cc];
        }
    }

    // epilogue: bias, write C, per-column partial stats
    float4 bb = *(const float4*)&bias[c0];
    float bbf[4] = {bb.x, bb.y, bb.z, bb.w};
    float scol[4] = {0.f, 0.f, 0.f, 0.f};
    float qcol[4] = {0.f, 0.f, 0.f, 0.f};
#pragma unroll
    for (int rr = 0; rr < 4; rr++) {
        int gr = row0 + r0 + rr;
        if (gr < NNODES) {
            float4 v;
            float vf[4];
#pragma unroll
            for (int cc = 0; cc < 4; cc++) {
                vf[cc] = acc[rr][cc] + bbf[cc];
                scol[cc] += vf[cc];
                qcol[cc] += vf[cc] * vf[cc];
            }
            v.x = vf[0]; v.y = vf[1]; v.z = vf[2]; v.w = vf[3];
            *(float4*)&C[gr * 128 + c0] = v;
        }
    }
    __syncthreads();
#pragma unroll
    for (int cc = 0; cc < 4; cc++) {
        a1s[rg * 128 + c0 + cc] = scol[cc];
        a2s[rg * 128 + c0 + cc] = qcol[cc];
    }
    __syncthreads();
    if (t < 128) {
        float s = 0.f, q = 0.f;
#pragma unroll
        for (int g = 0; g < 8; g++) {
            s += a1s[g * 128 + t];
            q += a2s[g * 128 + t];
        }
        atomicAdd(&stat[t], s);
        atomicAdd(&stat[128 + t], q);
    }
}

__global__ __launch_bounds__(128) void bn_coef(const float* __restrict__ stat,
                                               const float* __restrict__ gamma,
                                               const float* __restrict__ beta,
                                               float* __restrict__ coef) {
    int c = threadIdx.x;
    const float invM = 1.f / (float)NNODES;
    float mu = stat[c] * invM;
    float var = stat[128 + c] * invM - mu * mu;
    float inv = rsqrtf(var + BN_EPS);
    float sc = gamma[c] * inv;
    coef[c] = sc;
    coef[128 + c] = beta[c] - mu * sc;
}

// ---------------- BN apply + ReLU + xpool accumulation (float4) --------------
__global__ __launch_bounds__(256) void bn_apply(const float* __restrict__ Hin,
                                                float* __restrict__ Hout,
                                                const float* __restrict__ coef,
                                                const int* __restrict__ batch,
                                                float* __restrict__ pool,
                                                int layer, int relu) {
    int t = threadIdx.x;
    int lane = t & 31, grp = t >> 5;
    int c4 = lane * 4;
    float4 sc = *(const float4*)&coef[c4];
    float4 sh = *(const float4*)&coef[128 + c4];
    int row0 = blockIdx.x * 256;
    float4 accp = {0.f, 0.f, 0.f, 0.f};
    int curg = -1;
    float* pbase = pool + layer * 128 + c4;
    for (int rr = grp; rr < 256; rr += 8) {
        int r = row0 + rr;
        if (r >= NNODES) break;
        float4 v = *(const float4*)&Hin[r * 128 + c4];
        v.x = v.x * sc.x + sh.x;
        v.y = v.y * sc.y + sh.y;
        v.z = v.z * sc.z + sh.z;
        v.w = v.w * sc.w + sh.w;
        if (relu) {
            v.x = fmaxf(v.x, 0.f);
            v.y = fmaxf(v.y, 0.f);
            v.z = fmaxf(v.z, 0.f);
            v.w = fmaxf(v.w, 0.f);
        }
        *(float4*)&Hout[r * 128 + c4] = v;
        int g = batch[r];
        if (g != curg) {
            if (curg >= 0) {
                float* p = pbase + curg * 640;
                atomicAdd(p + 0, accp.x);
                atomicAdd(p + 1, accp.y);
                atomicAdd(p + 2, accp.z);
                atomicAdd(p + 3, accp.w);
            }
            curg = g;
            accp.x = accp.y = accp.z = accp.w = 0.f;
        }
        accp.x += v.x;
        accp.y += v.y;
        accp.z += v.z;
        accp.w += v.w;
    }
    if (curg >= 0) {
        float* p = pbase + curg * 640;
        atomicAdd(p + 0, accp.x);
        atomicAdd(p + 1, accp.y);
        atomicAdd(p + 2, accp.z);
        atomicAdd(p + 3, accp.w);
    }
}

extern "C" void kernel_launch(void* const* d_in, const int* in_sizes, int n_in,
                              void* d_out, int out_size, void* d_ws, size_t ws_size,
                              hipStream_t stream) {
    const int* batch = (const int*)d_in[0];
    const float* x = (const float*)d_in[1];
    const int* edge_index = (const int*)d_in[2];
    const float* edge_attr = (const float*)d_in[3];
    const float* edge_weight = (const float*)d_in[4];
    const float* W_atom = (const float*)d_in[5];
    const float* b_atom = (const float*)d_in[6];
    const float* W_bond = (const float*)d_in[7];
    const float* b_bond = (const float*)d_in[8];
    const float* Wl = (const float*)d_in[9];
    const float* bl = (const float*)d_in[10];
    const float* Wr = (const float*)d_in[11];
    const float* gamma = (const float*)d_in[12];
    const float* beta = (const float*)d_in[13];
    float* out = (float*)d_out;

    // ---- workspace layout ----
    char* ws = (char*)d_ws;
    size_t off = 0;
    auto alloc = [&](size_t bytes) -> void* {
        void* p = ws + off;
        off += (bytes + 255) & ~(size_t)255;
        return p;
    };
    float* hA = (float*)alloc((size_t)NNODES * 128 * 4);
    float* hB = (float*)alloc((size_t)NNODES * 128 * 4);
    float* agg = (float*)alloc((size_t)NNODES * 128 * 4);
    float* eagg = (float*)alloc((size_t)NNODES * 128 * 4);
    float* csr_w = (float*)alloc((size_t)NEDGES * 4);
    int* csr_src = (int*)alloc((size_t)NEDGES * 4);
    int* csr_eid = (int*)alloc((size_t)NEDGES * 4);
    int* rowptr = (int*)alloc((size_t)(NNODES + 1) * 4);
    int* cursor = (int*)alloc((size_t)NNODES * 4);
    int* deg = (int*)alloc((size_t)NNODES * 4);
    float* wsum = (float*)alloc((size_t)NNODES * 4);
    float* S = (float*)alloc((size_t)NNODES * 11 * 4);
    float* stat = (float*)alloc(NLAYERS * 256 * 4);
    float* coef = (float*)alloc(256 * 4);
    int* local_excl = (int*)alloc((size_t)NNODES * 4);
    int* part = (int*)alloc(SCAN_BLOCKS * 4);
    int* blockoff = (int*)alloc(SCAN_BLOCKS * 4);

    // ---- zero-init accumulation buffers ----
    hipMemsetAsync(out, 0, (size_t)NGRAPHS * 640 * 4, stream);  // xpool region
    hipMemsetAsync(deg, 0, (size_t)NNODES * 4, stream);
    hipMemsetAsync(stat, 0, NLAYERS * 256 * 4, stream);

    // ---- preprocessing ----
    deg_kernel<<<(NEDGES + 255) / 256, 256, 0, stream>>>(edge_index, deg);
    scan1<<<SCAN_BLOCKS, 256, 0, stream>>>(deg, local_excl, part);
    scan2<<<1, 256, 0, stream>>>(part, blockoff, rowptr);
    scan3<<<SCAN_BLOCKS, 256, 0, stream>>>(local_excl, blockoff, rowptr, cursor);
    edge_fill<<<(NEDGES + 255) / 256, 256, 0, stream>>>(edge_index, edge_weight, cursor,
                                                        csr_src, csr_w, csr_eid);
    node_S<<<(NNODES + 15) / 16, 256, 0, stream>>>(edge_attr, rowptr, csr_eid, csr_w,
                                                   S, wsum);
    enc_atom<<<(NNODES + 31) / 32, 256, 0, stream>>>(x, W_atom, b_atom, hA);
    enc_bond<<<(NNODES + 31) / 32, 256, 0, stream>>>(S, W_bond, b_bond, wsum, eagg);

    // ---- layers ----
    float* hcur = hA;
    for (int i = 0; i < NLAYERS; i++) {
        agg_kernel<<<(NNODES + 7) / 8, 256, 0, stream>>>(hcur, eagg, rowptr, csr_src,
                                                         csr_w, agg);
        layer_gemm<<<(NNODES + 31) / 32, 256, 0, stream>>>(agg, hcur,
                                                           Wl + (size_t)i * 128 * 128,
                                                           Wr + (size_t)i * 128 * 128,
                                                           bl + i * 128, hB,
                                                           stat + i * 256);
        bn_coef<<<1, 128, 0, stream>>>(stat + i * 256, gamma + i * 128, beta + i * 128,
                                       coef);
        float* dsth = (i == NLAYERS - 1) ? (out + (size_t)NGRAPHS * 640) : hcur;
        bn_apply<<<(NNODES + 255) / 256, 256, 0, stream>>>(hB, dsth, coef, batch, out, i,
                                                           (i < NLAYERS - 1) ? 1 : 0);
        hcur = dsth;
    }
}

// Round 4
// 851.782 us; speedup vs baseline: 2.4800x; 1.2126x over previous
//
#include <hip/hip_runtime.h>
#include <hip/hip_bf16.h>

#define NNODES 50000
#define NEDGES 600000
#define NGRAPHS 128
#define EMB 128
#define NLAYERS 5
#define BN_EPS 1e-5f
#define SCAN_BLOCKS ((NNODES + 255) / 256)  // 196

typedef short s16x8 __attribute__((ext_vector_type(8)));
typedef float f32x4 __attribute__((ext_vector_type(4)));

__device__ __forceinline__ short f2bf(float f) {
    unsigned u = __builtin_bit_cast(unsigned, f);
    unsigned r = (u + 0x7fffu + ((u >> 16) & 1u)) >> 16;  // RNE
    return (short)r;
}
__device__ __forceinline__ float bf2f(short s) {
    return __builtin_bit_cast(float, ((unsigned)(unsigned short)s) << 16);
}

// ---------------- deg histogram (int atomics only) ---------------------------
__global__ __launch_bounds__(256) void deg_kernel(const int* __restrict__ ei,
                                                  int* __restrict__ deg) {
    int e = blockIdx.x * 256 + threadIdx.x;
    if (e >= NEDGES) return;
    atomicAdd(&deg[ei[NEDGES + e]], 1);
}

// ---------------- multi-block scan ------------------------------------------
__global__ __launch_bounds__(256) void scan1(const int* __restrict__ deg,
                                             int* __restrict__ local_excl,
                                             int* __restrict__ part) {
    __shared__ int sh[256];
    int t = threadIdx.x;
    int i = blockIdx.x * 256 + t;
    int v = (i < NNODES) ? deg[i] : 0;
    sh[t] = v;
    __syncthreads();
    for (int off = 1; off < 256; off <<= 1) {
        int u = (t >= off) ? sh[t - off] : 0;
        __syncthreads();
        sh[t] += u;
        __syncthreads();
    }
    if (i < NNODES) local_excl[i] = sh[t] - v;
    if (t == 255) part[blockIdx.x] = sh[255];
}

__global__ __launch_bounds__(256) void scan2(int* __restrict__ part,
                                             int* __restrict__ blockoff,
                                             int* __restrict__ rowptr) {
    __shared__ int sh[256];
    int t = threadIdx.x;
    int v = (t < SCAN_BLOCKS) ? part[t] : 0;
    sh[t] = v;
    __syncthreads();
    for (int off = 1; off < 256; off <<= 1) {
        int u = (t >= off) ? sh[t - off] : 0;
        __syncthreads();
        sh[t] += u;
        __syncthreads();
    }
    if (t < SCAN_BLOCKS) blockoff[t] = sh[t] - v;
    if (t == 255) rowptr[NNODES] = sh[255];
}

__global__ __launch_bounds__(256) void scan3(const int* __restrict__ local_excl,
                                             const int* __restrict__ blockoff,
                                             int* __restrict__ rowptr,
                                             int* __restrict__ cursor) {
    int i = blockIdx.x * 256 + threadIdx.x;
    if (i >= NNODES) return;
    int v = local_excl[i] + blockoff[blockIdx.x];
    rowptr[i] = v;
    cursor[i] = v;
}

// ---------------- fill CSR (src, w, eid) -------------------------------------
__global__ __launch_bounds__(256) void edge_fill(const int* __restrict__ ei,
                                                 const float* __restrict__ ew,
                                                 int* __restrict__ cursor,
                                                 int* __restrict__ csr_src,
                                                 float* __restrict__ csr_w,
                                                 int* __restrict__ csr_eid) {
    int e = blockIdx.x * 256 + threadIdx.x;
    if (e >= NEDGES) return;
    int src = ei[e];
    int dst = ei[NEDGES + e];
    int pos = atomicAdd(&cursor[dst], 1);
    csr_src[pos] = src;
    csr_w[pos] = ew[e];
    csr_eid[pos] = e;
}

// ---------------- S[n,11], wsum[n] via CSR segmented sum ---------------------
__global__ __launch_bounds__(256) void node_S(const float* __restrict__ eattr,
                                              const int* __restrict__ rowptr,
                                              const int* __restrict__ csr_eid,
                                              const float* __restrict__ csr_w,
                                              float* __restrict__ S,
                                              float* __restrict__ wsum) {
    int t = threadIdx.x;
    int j = t & 15, grp = t >> 4;
    int node = blockIdx.x * 16 + grp;
    if (node >= NNODES) return;
    int b = rowptr[node], e = rowptr[node + 1];
    float s = 0.f;
    for (int p = b; p < e; p++) {
        int eid = csr_eid[p];
        float w = csr_w[p];
        if (j < 11) s += eattr[eid * 11 + j] * w;
        else if (j == 11) s += w;
    }
    if (j < 11) S[node * 11 + j] = s;
    else if (j == 11) wsum[node] = s;
}

// ---------------- encoder: h0 = x @ W_atom + b_atom  (K=48) ------------------
__global__ __launch_bounds__(256) void enc_atom(const float* __restrict__ X,
                                                const float* __restrict__ W,
                                                const float* __restrict__ b,
                                                float* __restrict__ H) {
    __shared__ float as[32 * 48];
    int row0 = blockIdx.x * 32;
    int t = threadIdx.x;
    for (int i = t; i < 32 * 48; i += 256) {
        int r = i / 48, c = i - r * 48;
        int gr = row0 + r;
        as[i] = (gr < NNODES) ? X[gr * 48 + c] : 0.f;
    }
    __syncthreads();
    int c = t & 127, rh = t >> 7;
    float acc[16];
#pragma unroll
    for (int i = 0; i < 16; i++) acc[i] = 0.f;
    for (int k = 0; k < 48; k++) {
        float w = W[k * 128 + c];
#pragma unroll
        for (int i = 0; i < 16; i++) acc[i] += as[(rh * 16 + i) * 48 + k] * w;
    }
    float bb = b[c];
    for (int i = 0; i < 16; i++) {
        int gr = row0 + rh * 16 + i;
        if (gr < NNODES) H[gr * 128 + c] = acc[i] + bb;
    }
}

// ---------------- eagg = S @ W_bond + b_bond * wsum  (K=11) ------------------
__global__ __launch_bounds__(256) void enc_bond(const float* __restrict__ S,
                                                const float* __restrict__ W,
                                                const float* __restrict__ b,
                                                const float* __restrict__ wsum,
                                                float* __restrict__ EA) {
    __shared__ float as[32 * 11];
    __shared__ float wss[32];
    int row0 = blockIdx.x * 32;
    int t = threadIdx.x;
    for (int i = t; i < 32 * 11; i += 256) {
        int r = i / 11, c = i - r * 11;
        int gr = row0 + r;
        as[i] = (gr < NNODES) ? S[gr * 11 + c] : 0.f;
    }
    if (t < 32) wss[t] = (row0 + t < NNODES) ? wsum[row0 + t] : 0.f;
    __syncthreads();
    int c = t & 127, rh = t >> 7;
    float acc[16];
#pragma unroll
    for (int i = 0; i < 16; i++) acc[i] = 0.f;
    for (int k = 0; k < 11; k++) {
        float w = W[k * 128 + c];
#pragma unroll
        for (int i = 0; i < 16; i++) acc[i] += as[(rh * 16 + i) * 11 + k] * w;
    }
    float bb = b[c];
    for (int i = 0; i < 16; i++) {
        int gr = row0 + rh * 16 + i;
        if (gr < NNODES) EA[gr * 128 + c] = acc[i] + bb * wss[rh * 16 + i];
    }
}

// ---------------- per-layer aggregation (float4, 2-edge unroll) --------------
__global__ __launch_bounds__(256) void agg_kernel(const float* __restrict__ H,
                                                  const float* __restrict__ eagg,
                                                  const int* __restrict__ rowptr,
                                                  const int* __restrict__ csr_src,
                                                  const float* __restrict__ csr_w,
                                                  float* __restrict__ agg) {
    int t = threadIdx.x;
    int lane = t & 31, grp = t >> 5;
    int c4 = lane * 4;
    int node = blockIdx.x * 8 + grp;
    if (node >= NNODES) return;
    int b = rowptr[node], e = rowptr[node + 1];
    float4 s = {0.f, 0.f, 0.f, 0.f};
    int p = b;
    for (; p + 1 < e; p += 2) {
        int s0 = csr_src[p], s1 = csr_src[p + 1];
        float w0 = csr_w[p], w1 = csr_w[p + 1];
        float4 h0 = *(const float4*)&H[s0 * 128 + c4];
        float4 h1 = *(const float4*)&H[s1 * 128 + c4];
        s.x += h0.x * w0 + h1.x * w1;
        s.y += h0.y * w0 + h1.y * w1;
        s.z += h0.z * w0 + h1.z * w1;
        s.w += h0.w * w0 + h1.w * w1;
    }
    if (p < e) {
        int s0 = csr_src[p];
        float w0 = csr_w[p];
        float4 h0 = *(const float4*)&H[s0 * 128 + c4];
        s.x += h0.x * w0;
        s.y += h0.y * w0;
        s.z += h0.z * w0;
        s.w += h0.w * w0;
    }
    float denom = fmaxf((float)(e - b), 1.f);
    float inv = 1.f / denom;
    float4 ea = *(const float4*)&eagg[node * 128 + c4];
    float4 o;
    o.x = (s.x + ea.x) * inv;
    o.y = (s.y + ea.y) * inv;
    o.z = (s.z + ea.z) * inv;
    o.w = (s.w + ea.w) * inv;
    *(float4*)&agg[node * 128 + c4] = o;
}

// ---------------- weight prep: hi/lo bf16 fragment-layout planes -------------
// Bf per layer: [kstep 8][hi 4096 | lo 4096] bf16; within plane:
// idx = ((ntile*4 + quad)*16 + n)*8 + j, where k = kstep*32 + quad*8 + j,
// col = ntile*16 + n, value = (k<128 ? Wl : Wr)[k%128][col].
__global__ __launch_bounds__(256) void bprep(const float* __restrict__ Wl,
                                             const float* __restrict__ Wr,
                                             short* __restrict__ Bf) {
    int idx = blockIdx.x * 256 + threadIdx.x;
    if (idx >= NLAYERS * 32768) return;
    int layer = idx >> 15;
    int r = idx & 32767;
    int k = r >> 7, col = r & 127;
    float w = (k < 128) ? Wl[layer * 16384 + k * 128 + col]
                        : Wr[layer * 16384 + (k - 128) * 128 + col];
    short hi = f2bf(w);
    short lo = f2bf(w - bf2f(hi));
    int kstep = k >> 5, quad = (k >> 3) & 3, j = k & 7;
    int ntile = col >> 4, n = col & 15;
    int fo = ((ntile * 4 + quad) * 16 + n) * 8 + j;
    short* base = Bf + (size_t)layer * 65536 + kstep * 8192;
    base[fo] = hi;
    base[4096 + fo] = lo;
}

// ---------------- MFMA GEMM: C = [agg|h] @ Bf + bias, fused BN stats ---------
// block: 256 thr = 4 waves, 64 rows; wave tile 16 rows x 128 cols.
__global__ __launch_bounds__(256) void layer_gemm(const float* __restrict__ Agg,
                                                  const float* __restrict__ H,
                                                  const short* __restrict__ Bf,
                                                  const float* __restrict__ bias,
                                                  float* __restrict__ C,
                                                  float* __restrict__ stat) {
    __shared__ short bs[2][8192];   // 16 KB per buffer
    __shared__ float s_s[128], s_q[128];
    int t = threadIdx.x;
    int wave = t >> 6, lane = t & 63;
    int n = lane & 15, quad = lane >> 4;
    int row0 = blockIdx.x * 64;

    if (t < 128) { s_s[t] = 0.f; s_q[t] = 0.f; }

    // stage kstep 0
    {
        const uint4* src = (const uint4*)Bf;
        uint4* dst = (uint4*)&bs[0][0];
        for (int i = t; i < 1024; i += 256) dst[i] = src[i];
    }

    int myrow = row0 + wave * 16 + n;          // A row for this lane
    bool rowok = myrow < NNODES;
    const float* arow_agg = Agg + (size_t)myrow * 128;
    const float* arow_h = H + (size_t)myrow * 128;

    f32x4 acc[8];
#pragma unroll
    for (int i = 0; i < 8; i++) acc[i] = (f32x4){0.f, 0.f, 0.f, 0.f};

    __syncthreads();

    for (int ks = 0; ks < 8; ks++) {
        // ---- A fragment: 8 fp32, split to hi/lo bf16 ----
        const float* ap = (ks < 4 ? arow_agg + ks * 32 : arow_h + (ks - 4) * 32) + quad * 8;
        float4 f0 = {0.f, 0.f, 0.f, 0.f}, f1 = {0.f, 0.f, 0.f, 0.f};
        if (rowok) {
            f0 = *(const float4*)(ap);
            f1 = *(const float4*)(ap + 4);
        }
        float fv[8] = {f0.x, f0.y, f0.z, f0.w, f1.x, f1.y, f1.z, f1.w};
        s16x8 ahi, alo;
#pragma unroll
        for (int j = 0; j < 8; j++) {
            short h = f2bf(fv[j]);
            ahi[j] = h;
            alo[j] = f2bf(fv[j] - bf2f(h));
        }
        // ---- stage next kstep into other buffer ----
        if (ks < 7) {
            const uint4* src = (const uint4*)(Bf + (ks + 1) * 8192);
            uint4* dst = (uint4*)&bs[(ks + 1) & 1][0];
            for (int i = t; i < 1024; i += 256) dst[i] = src[i];
        }
        // ---- 8 ntiles x 3 MFMAs ----
        const short* bb = &bs[ks & 1][0];
#pragma unroll
        for (int nt = 0; nt < 8; nt++) {
            int fo = ((nt * 4 + quad) * 16 + n) * 8;
            s16x8 bhi = *(const s16x8*)&bb[fo];
            s16x8 blo = *(const s16x8*)&bb[4096 + fo];
            acc[nt] = __builtin_amdgcn_mfma_f32_16x16x32_bf16(ahi, bhi, acc[nt], 0, 0, 0);
            acc[nt] = __builtin_amdgcn_mfma_f32_16x16x32_bf16(alo, bhi, acc[nt], 0, 0, 0);
            acc[nt] = __builtin_amdgcn_mfma_f32_16x16x32_bf16(ahi, blo, acc[nt], 0, 0, 0);
        }
        __syncthreads();
    }

    // ---- epilogue: bias, C write, fused BN partial stats ----
#pragma unroll
    for (int nt = 0; nt < 8; nt++) {
        int col = nt * 16 + n;
        float bb = bias[col];
        float ss = 0.f, qq = 0.f;
#pragma unroll
        for (int reg = 0; reg < 4; reg++) {
            int r = row0 + wave * 16 + quad * 4 + reg;
            if (r < NNODES) {
                float v = acc[nt][reg] + bb;
                C[(size_t)r * 128 + col] = v;
                ss += v;
                qq += v * v;
            }
        }
        ss += __shfl_xor(ss, 16);
        ss += __shfl_xor(ss, 32);
        qq += __shfl_xor(qq, 16);
        qq += __shfl_xor(qq, 32);
        if (quad == 0) {
            atomicAdd(&s_s[col], ss);
            atomicAdd(&s_q[col], qq);
        }
    }
    __syncthreads();
    if (t < 128) {
        atomicAdd(&stat[t], s_s[t]);
        atomicAdd(&stat[128 + t], s_q[t]);
    }
}

__global__ __launch_bounds__(128) void bn_coef(const float* __restrict__ stat,
                                               const float* __restrict__ gamma,
                                               const float* __restrict__ beta,
                                               float* __restrict__ coef) {
    int c = threadIdx.x;
    const float invM = 1.f / (float)NNODES;
    float mu = stat[c] * invM;
    float var = stat[128 + c] * invM - mu * mu;
    float inv = rsqrtf(var + BN_EPS);
    float sc = gamma[c] * inv;
    coef[c] = sc;
    coef[128 + c] = beta[c] - mu * sc;
}

// ---------------- BN apply + ReLU + xpool accumulation (float4) --------------
__global__ __launch_bounds__(256) void bn_apply(const float* __restrict__ Hin,
                                                float* __restrict__ Hout,
                                                const float* __restrict__ coef,
                                                const int* __restrict__ batch,
                                                float* __restrict__ pool,
                                                int layer, int relu) {
    int t = threadIdx.x;
    int lane = t & 31, grp = t >> 5;
    int c4 = lane * 4;
    float4 sc = *(const float4*)&coef[c4];
    float4 sh = *(const float4*)&coef[128 + c4];
    int row0 = blockIdx.x * 256;
    float4 accp = {0.f, 0.f, 0.f, 0.f};
    int curg = -1;
    float* pbase = pool + layer * 128 + c4;
    for (int rr = grp; rr < 256; rr += 8) {
        int r = row0 + rr;
        if (r >= NNODES) break;
        float4 v = *(const float4*)&Hin[r * 128 + c4];
        v.x = v.x * sc.x + sh.x;
        v.y = v.y * sc.y + sh.y;
        v.z = v.z * sc.z + sh.z;
        v.w = v.w * sc.w + sh.w;
        if (relu) {
            v.x = fmaxf(v.x, 0.f);
            v.y = fmaxf(v.y, 0.f);
            v.z = fmaxf(v.z, 0.f);
            v.w = fmaxf(v.w, 0.f);
        }
        *(float4*)&Hout[r * 128 + c4] = v;
        int g = batch[r];
        if (g != curg) {
            if (curg >= 0) {
                float* p = pbase + curg * 640;
                atomicAdd(p + 0, accp.x);
                atomicAdd(p + 1, accp.y);
                atomicAdd(p + 2, accp.z);
                atomicAdd(p + 3, accp.w);
            }
            curg = g;
            accp.x = accp.y = accp.z = accp.w = 0.f;
        }
        accp.x += v.x;
        accp.y += v.y;
        accp.z += v.z;
        accp.w += v.w;
    }
    if (curg >= 0) {
        float* p = pbase + curg * 640;
        atomicAdd(p + 0, accp.x);
        atomicAdd(p + 1, accp.y);
        atomicAdd(p + 2, accp.z);
        atomicAdd(p + 3, accp.w);
    }
}

extern "C" void kernel_launch(void* const* d_in, const int* in_sizes, int n_in,
                              void* d_out, int out_size, void* d_ws, size_t ws_size,
                              hipStream_t stream) {
    const int* batch = (const int*)d_in[0];
    const float* x = (const float*)d_in[1];
    const int* edge_index = (const int*)d_in[2];
    const float* edge_attr = (const float*)d_in[3];
    const float* edge_weight = (const float*)d_in[4];
    const float* W_atom = (const float*)d_in[5];
    const float* b_atom = (const float*)d_in[6];
    const float* W_bond = (const float*)d_in[7];
    const float* b_bond = (const float*)d_in[8];
    const float* Wl = (const float*)d_in[9];
    const float* bl = (const float*)d_in[10];
    const float* Wr = (const float*)d_in[11];
    const float* gamma = (const float*)d_in[12];
    const float* beta = (const float*)d_in[13];
    float* out = (float*)d_out;

    // ---- workspace layout ----
    char* ws = (char*)d_ws;
    size_t off = 0;
    auto alloc = [&](size_t bytes) -> void* {
        void* p = ws + off;
        off += (bytes + 255) & ~(size_t)255;
        return p;
    };
    float* hA = (float*)alloc((size_t)NNODES * 128 * 4);
    float* hB = (float*)alloc((size_t)NNODES * 128 * 4);
    float* agg = (float*)alloc((size_t)NNODES * 128 * 4);
    float* eagg = (float*)alloc((size_t)NNODES * 128 * 4);
    float* csr_w = (float*)alloc((size_t)NEDGES * 4);
    int* csr_src = (int*)alloc((size_t)NEDGES * 4);
    int* csr_eid = (int*)alloc((size_t)NEDGES * 4);
    int* rowptr = (int*)alloc((size_t)(NNODES + 1) * 4);
    int* cursor = (int*)alloc((size_t)NNODES * 4);
    int* deg = (int*)alloc((size_t)NNODES * 4);
    float* wsum = (float*)alloc((size_t)NNODES * 4);
    float* S = (float*)alloc((size_t)NNODES * 11 * 4);
    float* stat = (float*)alloc(NLAYERS * 256 * 4);
    float* coef = (float*)alloc(256 * 4);
    int* local_excl = (int*)alloc((size_t)NNODES * 4);
    int* part = (int*)alloc(SCAN_BLOCKS * 4);
    int* blockoff = (int*)alloc(SCAN_BLOCKS * 4);
    short* Bf = (short*)alloc((size_t)NLAYERS * 65536 * 2);

    // ---- zero-init accumulation buffers ----
    hipMemsetAsync(out, 0, (size_t)NGRAPHS * 640 * 4, stream);  // xpool region
    hipMemsetAsync(deg, 0, (size_t)NNODES * 4, stream);
    hipMemsetAsync(stat, 0, NLAYERS * 256 * 4, stream);

    // ---- preprocessing ----
    deg_kernel<<<(NEDGES + 255) / 256, 256, 0, stream>>>(edge_index, deg);
    scan1<<<SCAN_BLOCKS, 256, 0, stream>>>(deg, local_excl, part);
    scan2<<<1, 256, 0, stream>>>(part, blockoff, rowptr);
    scan3<<<SCAN_BLOCKS, 256, 0, stream>>>(local_excl, blockoff, rowptr, cursor);
    edge_fill<<<(NEDGES + 255) / 256, 256, 0, stream>>>(edge_index, edge_weight, cursor,
                                                        csr_src, csr_w, csr_eid);
    node_S<<<(NNODES + 15) / 16, 256, 0, stream>>>(edge_attr, rowptr, csr_eid, csr_w,
                                                   S, wsum);
    bprep<<<(NLAYERS * 32768 + 255) / 256, 256, 0, stream>>>(Wl, Wr, Bf);
    enc_atom<<<(NNODES + 31) / 32, 256, 0, stream>>>(x, W_atom, b_atom, hA);
    enc_bond<<<(NNODES + 31) / 32, 256, 0, stream>>>(S, W_bond, b_bond, wsum, eagg);

    // ---- layers ----
    float* hcur = hA;
    for (int i = 0; i < NLAYERS; i++) {
        agg_kernel<<<(NNODES + 7) / 8, 256, 0, stream>>>(hcur, eagg, rowptr, csr_src,
                                                         csr_w, agg);
        layer_gemm<<<(NNODES + 63) / 64, 256, 0, stream>>>(agg, hcur,
                                                           Bf + (size_t)i * 65536,
                                                           bl + i * 128, hB,
                                                           stat + i * 256);
        bn_coef<<<1, 128, 0, stream>>>(stat + i * 256, gamma + i * 128, beta + i * 128,
                                       coef);
        float* dsth = (i == NLAYERS - 1) ? (out + (size_t)NGRAPHS * 640) : hcur;
        bn_apply<<<(NNODES + 255) / 256, 256, 0, stream>>>(hB, dsth, coef, batch, out, i,
                                                           (i < NLAYERS - 1) ? 1 : 0);
        hcur = dsth;
    }
}

// Round 5
// 806.800 us; speedup vs baseline: 2.6183x; 1.0558x over previous
//
#include <hip/hip_runtime.h>
#include <hip/hip_bf16.h>

#define NNODES 50000
#define NEDGES 600000
#define NGRAPHS 128
#define EMB 128
#define NLAYERS 5
#define BN_EPS 1e-5f
#define SCAN_BLOCKS ((NNODES + 255) / 256)  // 196

typedef short s16x8 __attribute__((ext_vector_type(8)));
typedef float f32x4 __attribute__((ext_vector_type(4)));

__device__ __forceinline__ short f2bf(float f) {
    unsigned u = __builtin_bit_cast(unsigned, f);
    unsigned r = (u + 0x7fffu + ((u >> 16) & 1u)) >> 16;  // RNE
    return (short)r;
}
__device__ __forceinline__ float bf2f(short s) {
    return __builtin_bit_cast(float, ((unsigned)(unsigned short)s) << 16);
}

// ---------------- deg histogram (int atomics only) ---------------------------
__global__ __launch_bounds__(256) void deg_kernel(const int* __restrict__ ei,
                                                  int* __restrict__ deg) {
    int e = blockIdx.x * 256 + threadIdx.x;
    if (e >= NEDGES) return;
    atomicAdd(&deg[ei[NEDGES + e]], 1);
}

// ---------------- multi-block scan ------------------------------------------
__global__ __launch_bounds__(256) void scan1(const int* __restrict__ deg,
                                             int* __restrict__ local_excl,
                                             int* __restrict__ part) {
    __shared__ int sh[256];
    int t = threadIdx.x;
    int i = blockIdx.x * 256 + t;
    int v = (i < NNODES) ? deg[i] : 0;
    sh[t] = v;
    __syncthreads();
    for (int off = 1; off < 256; off <<= 1) {
        int u = (t >= off) ? sh[t - off] : 0;
        __syncthreads();
        sh[t] += u;
        __syncthreads();
    }
    if (i < NNODES) local_excl[i] = sh[t] - v;
    if (t == 255) part[blockIdx.x] = sh[255];
}

__global__ __launch_bounds__(256) void scan2(int* __restrict__ part,
                                             int* __restrict__ blockoff,
                                             int* __restrict__ rowptr) {
    __shared__ int sh[256];
    int t = threadIdx.x;
    int v = (t < SCAN_BLOCKS) ? part[t] : 0;
    sh[t] = v;
    __syncthreads();
    for (int off = 1; off < 256; off <<= 1) {
        int u = (t >= off) ? sh[t - off] : 0;
        __syncthreads();
        sh[t] += u;
        __syncthreads();
    }
    if (t < SCAN_BLOCKS) blockoff[t] = sh[t] - v;
    if (t == 255) rowptr[NNODES] = sh[255];
}

__global__ __launch_bounds__(256) void scan3(const int* __restrict__ local_excl,
                                             const int* __restrict__ blockoff,
                                             int* __restrict__ rowptr,
                                             int* __restrict__ cursor) {
    int i = blockIdx.x * 256 + threadIdx.x;
    if (i >= NNODES) return;
    int v = local_excl[i] + blockoff[blockIdx.x];
    rowptr[i] = v;
    cursor[i] = v;
}

// ---------------- fill CSR: single packed int4 {src, w, eid, 0} per edge -----
__global__ __launch_bounds__(256) void edge_fill(const int* __restrict__ ei,
                                                 const float* __restrict__ ew,
                                                 int* __restrict__ cursor,
                                                 int4* __restrict__ epack) {
    int e = blockIdx.x * 256 + threadIdx.x;
    if (e >= NEDGES) return;
    int src = ei[e];
    int dst = ei[NEDGES + e];
    int pos = atomicAdd(&cursor[dst], 1);
    int4 pk;
    pk.x = src;
    pk.y = __float_as_int(ew[e]);
    pk.z = e;
    pk.w = 0;
    epack[pos] = pk;
}

// ---------------- S[n,11], wsum[n] via CSR segmented sum ---------------------
__global__ __launch_bounds__(256) void node_S(const float* __restrict__ eattr,
                                              const int* __restrict__ rowptr,
                                              const int4* __restrict__ epack,
                                              float* __restrict__ S,
                                              float* __restrict__ wsum) {
    int t = threadIdx.x;
    int j = t & 15, grp = t >> 4;
    int node = blockIdx.x * 16 + grp;
    if (node >= NNODES) return;
    int b = rowptr[node], e = rowptr[node + 1];
    float s = 0.f;
    for (int p = b; p < e; p++) {
        int4 pk = epack[p];
        float w = __int_as_float(pk.y);
        int eid = pk.z;
        if (j < 11) s += eattr[eid * 11 + j] * w;
        else if (j == 11) s += w;
    }
    if (j < 11) S[node * 11 + j] = s;
    else if (j == 11) wsum[node] = s;
}

// ---------------- encoder: h0 = x @ W_atom + b_atom -> hi/lo planes ----------
__global__ __launch_bounds__(256) void enc_atom(const float* __restrict__ X,
                                                const float* __restrict__ W,
                                                const float* __restrict__ b,
                                                short* __restrict__ Hhi,
                                                short* __restrict__ Hlo) {
    __shared__ float as[32 * 48];
    int row0 = blockIdx.x * 32;
    int t = threadIdx.x;
    for (int i = t; i < 32 * 48; i += 256) {
        int r = i / 48, c = i - r * 48;
        int gr = row0 + r;
        as[i] = (gr < NNODES) ? X[gr * 48 + c] : 0.f;
    }
    __syncthreads();
    int c = t & 127, rh = t >> 7;
    float acc[16];
#pragma unroll
    for (int i = 0; i < 16; i++) acc[i] = 0.f;
    for (int k = 0; k < 48; k++) {
        float w = W[k * 128 + c];
#pragma unroll
        for (int i = 0; i < 16; i++) acc[i] += as[(rh * 16 + i) * 48 + k] * w;
    }
    float bb = b[c];
    for (int i = 0; i < 16; i++) {
        int gr = row0 + rh * 16 + i;
        if (gr < NNODES) {
            float v = acc[i] + bb;
            short hi = f2bf(v);
            Hhi[(size_t)gr * 128 + c] = hi;
            Hlo[(size_t)gr * 128 + c] = f2bf(v - bf2f(hi));
        }
    }
}

// ---------------- eagg = S @ W_bond + b_bond * wsum  (K=11) ------------------
__global__ __launch_bounds__(256) void enc_bond(const float* __restrict__ S,
                                                const float* __restrict__ W,
                                                const float* __restrict__ b,
                                                const float* __restrict__ wsum,
                                                float* __restrict__ EA) {
    __shared__ float as[32 * 11];
    __shared__ float wss[32];
    int row0 = blockIdx.x * 32;
    int t = threadIdx.x;
    for (int i = t; i < 32 * 11; i += 256) {
        int r = i / 11, c = i - r * 11;
        int gr = row0 + r;
        as[i] = (gr < NNODES) ? S[gr * 11 + c] : 0.f;
    }
    if (t < 32) wss[t] = (row0 + t < NNODES) ? wsum[row0 + t] : 0.f;
    __syncthreads();
    int c = t & 127, rh = t >> 7;
    float acc[16];
#pragma unroll
    for (int i = 0; i < 16; i++) acc[i] = 0.f;
    for (int k = 0; k < 11; k++) {
        float w = W[k * 128 + c];
#pragma unroll
        for (int i = 0; i < 16; i++) acc[i] += as[(rh * 16 + i) * 11 + k] * w;
    }
    float bb = b[c];
    for (int i = 0; i < 16; i++) {
        int gr = row0 + rh * 16 + i;
        if (gr < NNODES) EA[gr * 128 + c] = acc[i] + bb * wss[rh * 16 + i];
    }
}

// ---------------- per-layer aggregation: bf16-hi gather -> agg hi/lo planes --
__global__ __launch_bounds__(256) void agg_kernel(const short* __restrict__ Hhi,
                                                  const float* __restrict__ eagg,
                                                  const int* __restrict__ rowptr,
                                                  const int4* __restrict__ epack,
                                                  short* __restrict__ Ahi,
                                                  short* __restrict__ Alo) {
    int t = threadIdx.x;
    int lane = t & 31, grp = t >> 5;
    int c4 = lane * 4;
    int node = blockIdx.x * 8 + grp;
    if (node >= NNODES) return;
    int b = rowptr[node], e = rowptr[node + 1];
    float4 s = {0.f, 0.f, 0.f, 0.f};
    int p = b;
    for (; p + 1 < e; p += 2) {
        int4 p0 = epack[p], p1 = epack[p + 1];
        float w0 = __int_as_float(p0.y), w1 = __int_as_float(p1.y);
        ushort4 h0 = *(const ushort4*)&Hhi[(size_t)p0.x * 128 + c4];
        ushort4 h1 = *(const ushort4*)&Hhi[(size_t)p1.x * 128 + c4];
        s.x += bf2f(h0.x) * w0 + bf2f(h1.x) * w1;
        s.y += bf2f(h0.y) * w0 + bf2f(h1.y) * w1;
        s.z += bf2f(h0.z) * w0 + bf2f(h1.z) * w1;
        s.w += bf2f(h0.w) * w0 + bf2f(h1.w) * w1;
    }
    if (p < e) {
        int4 p0 = epack[p];
        float w0 = __int_as_float(p0.y);
        ushort4 h0 = *(const ushort4*)&Hhi[(size_t)p0.x * 128 + c4];
        s.x += bf2f(h0.x) * w0;
        s.y += bf2f(h0.y) * w0;
        s.z += bf2f(h0.z) * w0;
        s.w += bf2f(h0.w) * w0;
    }
    float inv = 1.f / fmaxf((float)(e - b), 1.f);
    float4 ea = *(const float4*)&eagg[(size_t)node * 128 + c4];
    float vf[4] = {(s.x + ea.x) * inv, (s.y + ea.y) * inv,
                   (s.z + ea.z) * inv, (s.w + ea.w) * inv};
    ushort4 hi4, lo4;
    short h;
    h = f2bf(vf[0]); hi4.x = h; lo4.x = f2bf(vf[0] - bf2f(h));
    h = f2bf(vf[1]); hi4.y = h; lo4.y = f2bf(vf[1] - bf2f(h));
    h = f2bf(vf[2]); hi4.z = h; lo4.z = f2bf(vf[2] - bf2f(h));
    h = f2bf(vf[3]); hi4.w = h; lo4.w = f2bf(vf[3] - bf2f(h));
    *(ushort4*)&Ahi[(size_t)node * 128 + c4] = hi4;
    *(ushort4*)&Alo[(size_t)node * 128 + c4] = lo4;
}

// ---------------- weight prep: hi/lo bf16 fragment-layout planes -------------
__global__ __launch_bounds__(256) void bprep(const float* __restrict__ Wl,
                                             const float* __restrict__ Wr,
                                             short* __restrict__ Bf) {
    int idx = blockIdx.x * 256 + threadIdx.x;
    if (idx >= NLAYERS * 32768) return;
    int layer = idx >> 15;
    int r = idx & 32767;
    int k = r >> 7, col = r & 127;
    float w = (k < 128) ? Wl[layer * 16384 + k * 128 + col]
                        : Wr[layer * 16384 + (k - 128) * 128 + col];
    short hi = f2bf(w);
    short lo = f2bf(w - bf2f(hi));
    int kstep = k >> 5, quad = (k >> 3) & 3, j = k & 7;
    int ntile = col >> 4, n = col & 15;
    int fo = ((ntile * 4 + quad) * 16 + n) * 8 + j;
    short* base = Bf + (size_t)layer * 65536 + kstep * 8192;
    base[fo] = hi;
    base[4096 + fo] = lo;
}

// ---------------- MFMA GEMM: C = [agg|h] @ Bf + bias, fused BN stats ---------
// A operands come pre-split as hi/lo bf16 planes -> direct fragment loads.
__global__ __launch_bounds__(256) void layer_gemm(const short* __restrict__ Ahi,
                                                  const short* __restrict__ Alo,
                                                  const short* __restrict__ Hhi,
                                                  const short* __restrict__ Hlo,
                                                  const short* __restrict__ Bf,
                                                  const float* __restrict__ bias,
                                                  float* __restrict__ C,
                                                  float* __restrict__ stat) {
    __shared__ short bs[2][8192];
    __shared__ float s_s[128], s_q[128];
    int t = threadIdx.x;
    int wave = t >> 6, lane = t & 63;
    int n = lane & 15, quad = lane >> 4;
    int row0 = blockIdx.x * 64;

    if (t < 128) { s_s[t] = 0.f; s_q[t] = 0.f; }

    {
        const uint4* src = (const uint4*)Bf;
        uint4* dst = (uint4*)&bs[0][0];
        for (int i = t; i < 1024; i += 256) dst[i] = src[i];
    }

    int myrow = row0 + wave * 16 + n;
    bool rowok = myrow < NNODES;
    size_t rbase = (size_t)myrow * 128;

    f32x4 acc[8];
#pragma unroll
    for (int i = 0; i < 8; i++) acc[i] = (f32x4){0.f, 0.f, 0.f, 0.f};

    __syncthreads();

    for (int ks = 0; ks < 8; ks++) {
        // ---- A fragments: direct hi/lo bf16 loads ----
        const short* hip = (ks < 4 ? Ahi : Hhi) + rbase + (ks & 3) * 32 + quad * 8;
        const short* lop = (ks < 4 ? Alo : Hlo) + rbase + (ks & 3) * 32 + quad * 8;
        s16x8 ahi = {0, 0, 0, 0, 0, 0, 0, 0}, alo = {0, 0, 0, 0, 0, 0, 0, 0};
        if (rowok) {
            ahi = *(const s16x8*)hip;
            alo = *(const s16x8*)lop;
        }
        // ---- stage next kstep ----
        if (ks < 7) {
            const uint4* src = (const uint4*)(Bf + (ks + 1) * 8192);
            uint4* dst = (uint4*)&bs[(ks + 1) & 1][0];
            for (int i = t; i < 1024; i += 256) dst[i] = src[i];
        }
        const short* bb = &bs[ks & 1][0];
#pragma unroll
        for (int nt = 0; nt < 8; nt++) {
            int fo = ((nt * 4 + quad) * 16 + n) * 8;
            s16x8 bhi = *(const s16x8*)&bb[fo];
            s16x8 blo = *(const s16x8*)&bb[4096 + fo];
            acc[nt] = __builtin_amdgcn_mfma_f32_16x16x32_bf16(ahi, bhi, acc[nt], 0, 0, 0);
            acc[nt] = __builtin_amdgcn_mfma_f32_16x16x32_bf16(alo, bhi, acc[nt], 0, 0, 0);
            acc[nt] = __builtin_amdgcn_mfma_f32_16x16x32_bf16(ahi, blo, acc[nt], 0, 0, 0);
        }
        __syncthreads();
    }

#pragma unroll
    for (int nt = 0; nt < 8; nt++) {
        int col = nt * 16 + n;
        float bb = bias[col];
        float ss = 0.f, qq = 0.f;
#pragma unroll
        for (int reg = 0; reg < 4; reg++) {
            int r = row0 + wave * 16 + quad * 4 + reg;
            if (r < NNODES) {
                float v = acc[nt][reg] + bb;
                C[(size_t)r * 128 + col] = v;
                ss += v;
                qq += v * v;
            }
        }
        ss += __shfl_xor(ss, 16);
        ss += __shfl_xor(ss, 32);
        qq += __shfl_xor(qq, 16);
        qq += __shfl_xor(qq, 32);
        if (quad == 0) {
            atomicAdd(&s_s[col], ss);
            atomicAdd(&s_q[col], qq);
        }
    }
    __syncthreads();
    if (t < 128) {
        atomicAdd(&stat[t], s_s[t]);
        atomicAdd(&stat[128 + t], s_q[t]);
    }
}

__global__ __launch_bounds__(128) void bn_coef(const float* __restrict__ stat,
                                               const float* __restrict__ gamma,
                                               const float* __restrict__ beta,
                                               float* __restrict__ coef) {
    int c = threadIdx.x;
    const float invM = 1.f / (float)NNODES;
    float mu = stat[c] * invM;
    float var = stat[128 + c] * invM - mu * mu;
    float inv = rsqrtf(var + BN_EPS);
    float sc = gamma[c] * inv;
    coef[c] = sc;
    coef[128 + c] = beta[c] - mu * sc;
}

// ---------------- BN apply + ReLU + xpool; writes hi/lo planes or fp32 -------
__global__ __launch_bounds__(256) void bn_apply(const float* __restrict__ Hin,
                                                short* __restrict__ Hhi,
                                                short* __restrict__ Hlo,
                                                float* __restrict__ Hf32,
                                                const float* __restrict__ coef,
                                                const int* __restrict__ batch,
                                                float* __restrict__ pool,
                                                int layer, int relu) {
    int t = threadIdx.x;
    int lane = t & 31, grp = t >> 5;
    int c4 = lane * 4;
    float4 sc = *(const float4*)&coef[c4];
    float4 sh = *(const float4*)&coef[128 + c4];
    int row0 = blockIdx.x * 256;
    float4 accp = {0.f, 0.f, 0.f, 0.f};
    int curg = -1;
    float* pbase = pool + layer * 128 + c4;
    for (int rr = grp; rr < 256; rr += 8) {
        int r = row0 + rr;
        if (r >= NNODES) break;
        float4 v = *(const float4*)&Hin[(size_t)r * 128 + c4];
        v.x = v.x * sc.x + sh.x;
        v.y = v.y * sc.y + sh.y;
        v.z = v.z * sc.z + sh.z;
        v.w = v.w * sc.w + sh.w;
        if (relu) {
            v.x = fmaxf(v.x, 0.f);
            v.y = fmaxf(v.y, 0.f);
            v.z = fmaxf(v.z, 0.f);
            v.w = fmaxf(v.w, 0.f);
        }
        if (Hf32) {
            *(float4*)&Hf32[(size_t)r * 128 + c4] = v;
        } else {
            float vf[4] = {v.x, v.y, v.z, v.w};
            ushort4 hi4, lo4;
            short h;
            h = f2bf(vf[0]); hi4.x = h; lo4.x = f2bf(vf[0] - bf2f(h));
            h = f2bf(vf[1]); hi4.y = h; lo4.y = f2bf(vf[1] - bf2f(h));
            h = f2bf(vf[2]); hi4.z = h; lo4.z = f2bf(vf[2] - bf2f(h));
            h = f2bf(vf[3]); hi4.w = h; lo4.w = f2bf(vf[3] - bf2f(h));
            *(ushort4*)&Hhi[(size_t)r * 128 + c4] = hi4;
            *(ushort4*)&Hlo[(size_t)r * 128 + c4] = lo4;
        }
        int g = batch[r];
        if (g != curg) {
            if (curg >= 0) {
                float* p = pbase + curg * 640;
                atomicAdd(p + 0, accp.x);
                atomicAdd(p + 1, accp.y);
                atomicAdd(p + 2, accp.z);
                atomicAdd(p + 3, accp.w);
            }
            curg = g;
            accp.x = accp.y = accp.z = accp.w = 0.f;
        }
        accp.x += v.x;
        accp.y += v.y;
        accp.z += v.z;
        accp.w += v.w;
    }
    if (curg >= 0) {
        float* p = pbase + curg * 640;
        atomicAdd(p + 0, accp.x);
        atomicAdd(p + 1, accp.y);
        atomicAdd(p + 2, accp.z);
        atomicAdd(p + 3, accp.w);
    }
}

extern "C" void kernel_launch(void* const* d_in, const int* in_sizes, int n_in,
                              void* d_out, int out_size, void* d_ws, size_t ws_size,
                              hipStream_t stream) {
    const int* batch = (const int*)d_in[0];
    const float* x = (const float*)d_in[1];
    const int* edge_index = (const int*)d_in[2];
    const float* edge_attr = (const float*)d_in[3];
    const float* edge_weight = (const float*)d_in[4];
    const float* W_atom = (const float*)d_in[5];
    const float* b_atom = (const float*)d_in[6];
    const float* W_bond = (const float*)d_in[7];
    const float* b_bond = (const float*)d_in[8];
    const float* Wl = (const float*)d_in[9];
    const float* bl = (const float*)d_in[10];
    const float* Wr = (const float*)d_in[11];
    const float* gamma = (const float*)d_in[12];
    const float* beta = (const float*)d_in[13];
    float* out = (float*)d_out;

    // ---- workspace layout ----
    char* ws = (char*)d_ws;
    size_t off = 0;
    auto alloc = [&](size_t bytes) -> void* {
        void* p = ws + off;
        off += (bytes + 255) & ~(size_t)255;
        return p;
    };
    short* Hhi = (short*)alloc((size_t)NNODES * 128 * 2);
    short* Hlo = (short*)alloc((size_t)NNODES * 128 * 2);
    short* Ahi = (short*)alloc((size_t)NNODES * 128 * 2);
    short* Alo = (short*)alloc((size_t)NNODES * 128 * 2);
    float* hB = (float*)alloc((size_t)NNODES * 128 * 4);
    float* eagg = (float*)alloc((size_t)NNODES * 128 * 4);
    int4* epack = (int4*)alloc((size_t)NEDGES * 16);
    int* rowptr = (int*)alloc((size_t)(NNODES + 1) * 4);
    int* cursor = (int*)alloc((size_t)NNODES * 4);
    int* deg = (int*)alloc((size_t)NNODES * 4);
    float* wsum = (float*)alloc((size_t)NNODES * 4);
    float* S = (float*)alloc((size_t)NNODES * 11 * 4);
    float* stat = (float*)alloc(NLAYERS * 256 * 4);
    float* coef = (float*)alloc(256 * 4);
    int* local_excl = (int*)alloc((size_t)NNODES * 4);
    int* part = (int*)alloc(SCAN_BLOCKS * 4);
    int* blockoff = (int*)alloc(SCAN_BLOCKS * 4);
    short* Bf = (short*)alloc((size_t)NLAYERS * 65536 * 2);

    // ---- zero-init accumulation buffers ----
    hipMemsetAsync(out, 0, (size_t)NGRAPHS * 640 * 4, stream);
    hipMemsetAsync(deg, 0, (size_t)NNODES * 4, stream);
    hipMemsetAsync(stat, 0, NLAYERS * 256 * 4, stream);

    // ---- preprocessing ----
    deg_kernel<<<(NEDGES + 255) / 256, 256, 0, stream>>>(edge_index, deg);
    scan1<<<SCAN_BLOCKS, 256, 0, stream>>>(deg, local_excl, part);
    scan2<<<1, 256, 0, stream>>>(part, blockoff, rowptr);
    scan3<<<SCAN_BLOCKS, 256, 0, stream>>>(local_excl, blockoff, rowptr, cursor);
    edge_fill<<<(NEDGES + 255) / 256, 256, 0, stream>>>(edge_index, edge_weight, cursor,
                                                        epack);
    node_S<<<(NNODES + 15) / 16, 256, 0, stream>>>(edge_attr, rowptr, epack, S, wsum);
    bprep<<<(NLAYERS * 32768 + 255) / 256, 256, 0, stream>>>(Wl, Wr, Bf);
    enc_atom<<<(NNODES + 31) / 32, 256, 0, stream>>>(x, W_atom, b_atom, Hhi, Hlo);
    enc_bond<<<(NNODES + 31) / 32, 256, 0, stream>>>(S, W_bond, b_bond, wsum, eagg);

    // ---- layers ----
    for (int i = 0; i < NLAYERS; i++) {
        agg_kernel<<<(NNODES + 7) / 8, 256, 0, stream>>>(Hhi, eagg, rowptr, epack,
                                                         Ahi, Alo);
        layer_gemm<<<(NNODES + 63) / 64, 256, 0, stream>>>(Ahi, Alo, Hhi, Hlo,
                                                           Bf + (size_t)i * 65536,
                                                           bl + i * 128, hB,
                                                           stat + i * 256);
        bn_coef<<<1, 128, 0, stream>>>(stat + i * 256, gamma + i * 128, beta + i * 128,
                                       coef);
        int last = (i == NLAYERS - 1);
        bn_apply<<<(NNODES + 255) / 256, 256, 0, stream>>>(
            hB, Hhi, Hlo, last ? (out + (size_t)NGRAPHS * 640) : nullptr, coef, batch,
            out, i, last ? 0 : 1);
    }
}

// Round 6
// 803.007 us; speedup vs baseline: 2.6307x; 1.0047x over previous
//
#include <hip/hip_runtime.h>
#include <hip/hip_bf16.h>

#define NNODES 50000
#define NEDGES 600000
#define NGRAPHS 128
#define EMB 128
#define NLAYERS 5
#define BN_EPS 1e-5f
#define SCAN_BLOCKS ((NNODES + 255) / 256)  // 196

typedef short s16x8 __attribute__((ext_vector_type(8)));
typedef float f32x4 __attribute__((ext_vector_type(4)));

__device__ __forceinline__ short f2bf(float f) {
    unsigned u = __builtin_bit_cast(unsigned, f);
    unsigned r = (u + 0x7fffu + ((u >> 16) & 1u)) >> 16;  // RNE
    return (short)r;
}
__device__ __forceinline__ float bf2f(short s) {
    return __builtin_bit_cast(float, ((unsigned)(unsigned short)s) << 16);
}

// ---------------- deg histogram (int atomics only) ---------------------------
__global__ __launch_bounds__(256) void deg_kernel(const int* __restrict__ ei,
                                                  int* __restrict__ deg) {
    int e = blockIdx.x * 256 + threadIdx.x;
    if (e >= NEDGES) return;
    atomicAdd(&deg[ei[NEDGES + e]], 1);
}

// ---------------- multi-block scan ------------------------------------------
__global__ __launch_bounds__(256) void scan1(const int* __restrict__ deg,
                                             int* __restrict__ local_excl,
                                             int* __restrict__ part) {
    __shared__ int sh[256];
    int t = threadIdx.x;
    int i = blockIdx.x * 256 + t;
    int v = (i < NNODES) ? deg[i] : 0;
    sh[t] = v;
    __syncthreads();
    for (int off = 1; off < 256; off <<= 1) {
        int u = (t >= off) ? sh[t - off] : 0;
        __syncthreads();
        sh[t] += u;
        __syncthreads();
    }
    if (i < NNODES) local_excl[i] = sh[t] - v;
    if (t == 255) part[blockIdx.x] = sh[255];
}

__global__ __launch_bounds__(256) void scan2(int* __restrict__ part,
                                             int* __restrict__ blockoff,
                                             int* __restrict__ rowptr) {
    __shared__ int sh[256];
    int t = threadIdx.x;
    int v = (t < SCAN_BLOCKS) ? part[t] : 0;
    sh[t] = v;
    __syncthreads();
    for (int off = 1; off < 256; off <<= 1) {
        int u = (t >= off) ? sh[t - off] : 0;
        __syncthreads();
        sh[t] += u;
        __syncthreads();
    }
    if (t < SCAN_BLOCKS) blockoff[t] = sh[t] - v;
    if (t == 255) rowptr[NNODES] = sh[255];
}

__global__ __launch_bounds__(256) void scan3(const int* __restrict__ local_excl,
                                             const int* __restrict__ blockoff,
                                             int* __restrict__ rowptr,
                                             int* __restrict__ cursor) {
    int i = blockIdx.x * 256 + threadIdx.x;
    if (i >= NNODES) return;
    int v = local_excl[i] + blockoff[blockIdx.x];
    rowptr[i] = v;
    cursor[i] = v;
}

// ---------------- fill CSR: single packed int4 {src, w, eid, 0} per edge -----
__global__ __launch_bounds__(256) void edge_fill(const int* __restrict__ ei,
                                                 const float* __restrict__ ew,
                                                 int* __restrict__ cursor,
                                                 int4* __restrict__ epack) {
    int e = blockIdx.x * 256 + threadIdx.x;
    if (e >= NEDGES) return;
    int src = ei[e];
    int dst = ei[NEDGES + e];
    int pos = atomicAdd(&cursor[dst], 1);
    int4 pk;
    pk.x = src;
    pk.y = __float_as_int(ew[e]);
    pk.z = e;
    pk.w = 0;
    epack[pos] = pk;
}

// ---------------- S[n,11], wsum[n] via CSR segmented sum ---------------------
__global__ __launch_bounds__(256) void node_S(const float* __restrict__ eattr,
                                              const int* __restrict__ rowptr,
                                              const int4* __restrict__ epack,
                                              float* __restrict__ S,
                                              float* __restrict__ wsum) {
    int t = threadIdx.x;
    int j = t & 15, grp = t >> 4;
    int node = blockIdx.x * 16 + grp;
    if (node >= NNODES) return;
    int b = rowptr[node], e = rowptr[node + 1];
    float s = 0.f;
    for (int p = b; p < e; p++) {
        int4 pk = epack[p];
        float w = __int_as_float(pk.y);
        int eid = pk.z;
        if (j < 11) s += eattr[eid * 11 + j] * w;
        else if (j == 11) s += w;
    }
    if (j < 11) S[node * 11 + j] = s;
    else if (j == 11) wsum[node] = s;
}

// ---------------- encoder: h0 = x @ W_atom + b_atom -> hi/lo planes ----------
__global__ __launch_bounds__(256) void enc_atom(const float* __restrict__ X,
                                                const float* __restrict__ W,
                                                const float* __restrict__ b,
                                                short* __restrict__ Hhi,
                                                short* __restrict__ Hlo) {
    __shared__ float as[32 * 48];
    int row0 = blockIdx.x * 32;
    int t = threadIdx.x;
    for (int i = t; i < 32 * 48; i += 256) {
        int r = i / 48, c = i - r * 48;
        int gr = row0 + r;
        as[i] = (gr < NNODES) ? X[gr * 48 + c] : 0.f;
    }
    __syncthreads();
    int c = t & 127, rh = t >> 7;
    float acc[16];
#pragma unroll
    for (int i = 0; i < 16; i++) acc[i] = 0.f;
    for (int k = 0; k < 48; k++) {
        float w = W[k * 128 + c];
#pragma unroll
        for (int i = 0; i < 16; i++) acc[i] += as[(rh * 16 + i) * 48 + k] * w;
    }
    float bb = b[c];
    for (int i = 0; i < 16; i++) {
        int gr = row0 + rh * 16 + i;
        if (gr < NNODES) {
            float v = acc[i] + bb;
            short hi = f2bf(v);
            Hhi[(size_t)gr * 128 + c] = hi;
            Hlo[(size_t)gr * 128 + c] = f2bf(v - bf2f(hi));
        }
    }
}

// ---------------- eagg = S @ W_bond + b_bond * wsum  (K=11) ------------------
__global__ __launch_bounds__(256) void enc_bond(const float* __restrict__ S,
                                                const float* __restrict__ W,
                                                const float* __restrict__ b,
                                                const float* __restrict__ wsum,
                                                float* __restrict__ EA) {
    __shared__ float as[32 * 11];
    __shared__ float wss[32];
    int row0 = blockIdx.x * 32;
    int t = threadIdx.x;
    for (int i = t; i < 32 * 11; i += 256) {
        int r = i / 11, c = i - r * 11;
        int gr = row0 + r;
        as[i] = (gr < NNODES) ? S[gr * 11 + c] : 0.f;
    }
    if (t < 32) wss[t] = (row0 + t < NNODES) ? wsum[row0 + t] : 0.f;
    __syncthreads();
    int c = t & 127, rh = t >> 7;
    float acc[16];
#pragma unroll
    for (int i = 0; i < 16; i++) acc[i] = 0.f;
    for (int k = 0; k < 11; k++) {
        float w = W[k * 128 + c];
#pragma unroll
        for (int i = 0; i < 16; i++) acc[i] += as[(rh * 16 + i) * 11 + k] * w;
    }
    float bb = b[c];
    for (int i = 0; i < 16; i++) {
        int gr = row0 + rh * 16 + i;
        if (gr < NNODES) EA[gr * 128 + c] = acc[i] + bb * wss[rh * 16 + i];
    }
}

// ---------------- per-layer aggregation: bf16-hi gather -> agg hi/lo planes --
__global__ __launch_bounds__(256) void agg_kernel(const short* __restrict__ Hhi,
                                                  const float* __restrict__ eagg,
                                                  const int* __restrict__ rowptr,
                                                  const int4* __restrict__ epack,
                                                  short* __restrict__ Ahi,
                                                  short* __restrict__ Alo) {
    int t = threadIdx.x;
    int lane = t & 31, grp = t >> 5;
    int c4 = lane * 4;
    int node = blockIdx.x * 8 + grp;
    if (node >= NNODES) return;
    int b = rowptr[node], e = rowptr[node + 1];
    float4 s = {0.f, 0.f, 0.f, 0.f};
    int p = b;
    for (; p + 1 < e; p += 2) {
        int4 p0 = epack[p], p1 = epack[p + 1];
        float w0 = __int_as_float(p0.y), w1 = __int_as_float(p1.y);
        ushort4 h0 = *(const ushort4*)&Hhi[(size_t)p0.x * 128 + c4];
        ushort4 h1 = *(const ushort4*)&Hhi[(size_t)p1.x * 128 + c4];
        s.x += bf2f(h0.x) * w0 + bf2f(h1.x) * w1;
        s.y += bf2f(h0.y) * w0 + bf2f(h1.y) * w1;
        s.z += bf2f(h0.z) * w0 + bf2f(h1.z) * w1;
        s.w += bf2f(h0.w) * w0 + bf2f(h1.w) * w1;
    }
    if (p < e) {
        int4 p0 = epack[p];
        float w0 = __int_as_float(p0.y);
        ushort4 h0 = *(const ushort4*)&Hhi[(size_t)p0.x * 128 + c4];
        s.x += bf2f(h0.x) * w0;
        s.y += bf2f(h0.y) * w0;
        s.z += bf2f(h0.z) * w0;
        s.w += bf2f(h0.w) * w0;
    }
    float inv = 1.f / fmaxf((float)(e - b), 1.f);
    float4 ea = *(const float4*)&eagg[(size_t)node * 128 + c4];
    float vf[4] = {(s.x + ea.x) * inv, (s.y + ea.y) * inv,
                   (s.z + ea.z) * inv, (s.w + ea.w) * inv};
    ushort4 hi4, lo4;
    short h;
    h = f2bf(vf[0]); hi4.x = h; lo4.x = f2bf(vf[0] - bf2f(h));
    h = f2bf(vf[1]); hi4.y = h; lo4.y = f2bf(vf[1] - bf2f(h));
    h = f2bf(vf[2]); hi4.z = h; lo4.z = f2bf(vf[2] - bf2f(h));
    h = f2bf(vf[3]); hi4.w = h; lo4.w = f2bf(vf[3] - bf2f(h));
    *(ushort4*)&Ahi[(size_t)node * 128 + c4] = hi4;
    *(ushort4*)&Alo[(size_t)node * 128 + c4] = lo4;
}

// ---------------- weight prep: hi/lo bf16 fragment-layout planes -------------
__global__ __launch_bounds__(256) void bprep(const float* __restrict__ Wl,
                                             const float* __restrict__ Wr,
                                             short* __restrict__ Bf) {
    int idx = blockIdx.x * 256 + threadIdx.x;
    if (idx >= NLAYERS * 32768) return;
    int layer = idx >> 15;
    int r = idx & 32767;
    int k = r >> 7, col = r & 127;
    float w = (k < 128) ? Wl[layer * 16384 + k * 128 + col]
                        : Wr[layer * 16384 + (k - 128) * 128 + col];
    short hi = f2bf(w);
    short lo = f2bf(w - bf2f(hi));
    int kstep = k >> 5, quad = (k >> 3) & 3, j = k & 7;
    int ntile = col >> 4, n = col & 15;
    int fo = ((ntile * 4 + quad) * 16 + n) * 8 + j;
    short* base = Bf + (size_t)layer * 65536 + kstep * 8192;
    base[fo] = hi;
    base[4096 + fo] = lo;
}

// ---------------- MFMA GEMM: C = [agg|h] @ Bf + bias, fused BN stats ---------
// No LDS staging: B fragments loaded straight from L2-resident Bf into VGPRs;
// zero barriers in the K-loop, waves fully independent.
__global__ __launch_bounds__(256) void layer_gemm(const short* __restrict__ Ahi,
                                                  const short* __restrict__ Alo,
                                                  const short* __restrict__ Hhi,
                                                  const short* __restrict__ Hlo,
                                                  const short* __restrict__ Bf,
                                                  const float* __restrict__ bias,
                                                  float* __restrict__ C,
                                                  float* __restrict__ stat) {
    __shared__ float s_s[128], s_q[128];
    int t = threadIdx.x;
    int wave = t >> 6, lane = t & 63;
    int n = lane & 15, quad = lane >> 4;
    int row0 = blockIdx.x * 64;

    if (t < 128) { s_s[t] = 0.f; s_q[t] = 0.f; }
    __syncthreads();

    int myrow = row0 + wave * 16 + n;
    bool rowok = myrow < NNODES;
    size_t rbase = (size_t)myrow * 128;

    f32x4 acc[8];
#pragma unroll
    for (int i = 0; i < 8; i++) acc[i] = (f32x4){0.f, 0.f, 0.f, 0.f};

    // per-lane base into Bf fragment layout: fo = nt*512 + quad*128 + n*8
    const short* bb0 = Bf + quad * 128 + n * 8;

#pragma unroll 1
    for (int ks = 0; ks < 8; ks++) {
        const short* hsrc = (ks < 4) ? Ahi : Hhi;
        const short* lsrc = (ks < 4) ? Alo : Hlo;
        s16x8 ahi = {0, 0, 0, 0, 0, 0, 0, 0}, alo = {0, 0, 0, 0, 0, 0, 0, 0};
        if (rowok) {
            ahi = *(const s16x8*)(hsrc + rbase + (ks & 3) * 32 + quad * 8);
            alo = *(const s16x8*)(lsrc + rbase + (ks & 3) * 32 + quad * 8);
        }
        const short* bb = bb0 + ks * 8192;
#pragma unroll
        for (int nt = 0; nt < 8; nt++) {
            s16x8 bhi = *(const s16x8*)(bb + nt * 512);
            s16x8 blo = *(const s16x8*)(bb + 4096 + nt * 512);
            acc[nt] = __builtin_amdgcn_mfma_f32_16x16x32_bf16(ahi, bhi, acc[nt], 0, 0, 0);
            acc[nt] = __builtin_amdgcn_mfma_f32_16x16x32_bf16(alo, bhi, acc[nt], 0, 0, 0);
            acc[nt] = __builtin_amdgcn_mfma_f32_16x16x32_bf16(ahi, blo, acc[nt], 0, 0, 0);
        }
    }

#pragma unroll
    for (int nt = 0; nt < 8; nt++) {
        int col = nt * 16 + n;
        float bb = bias[col];
        float ss = 0.f, qq = 0.f;
#pragma unroll
        for (int reg = 0; reg < 4; reg++) {
            int r = row0 + wave * 16 + quad * 4 + reg;
            if (r < NNODES) {
                float v = acc[nt][reg] + bb;
                C[(size_t)r * 128 + col] = v;
                ss += v;
                qq += v * v;
            }
        }
        ss += __shfl_xor(ss, 16);
        ss += __shfl_xor(ss, 32);
        qq += __shfl_xor(qq, 16);
        qq += __shfl_xor(qq, 32);
        if (quad == 0) {
            atomicAdd(&s_s[col], ss);
            atomicAdd(&s_q[col], qq);
        }
    }
    __syncthreads();
    if (t < 128) {
        atomicAdd(&stat[t], s_s[t]);
        atomicAdd(&stat[128 + t], s_q[t]);
    }
}

// ---------------- BN apply (+inline coef) + ReLU + xpool ---------------------
__global__ __launch_bounds__(256) void bn_apply(const float* __restrict__ Hin,
                                                short* __restrict__ Hhi,
                                                short* __restrict__ Hlo,
                                                float* __restrict__ Hf32,
                                                const float* __restrict__ stat,
                                                const float* __restrict__ gamma,
                                                const float* __restrict__ beta,
                                                const int* __restrict__ batch,
                                                float* __restrict__ pool,
                                                int layer, int relu) {
    __shared__ float csc[128], csh[128];
    int t = threadIdx.x;
    if (t < 128) {
        const float invM = 1.f / (float)NNODES;
        float mu = stat[t] * invM;
        float var = stat[128 + t] * invM - mu * mu;
        float inv = rsqrtf(var + BN_EPS);
        float sc = gamma[t] * inv;
        csc[t] = sc;
        csh[t] = beta[t] - mu * sc;
    }
    __syncthreads();
    int lane = t & 31, grp = t >> 5;
    int c4 = lane * 4;
    float4 sc = *(const float4*)&csc[c4];
    float4 sh = *(const float4*)&csh[c4];
    int row0 = blockIdx.x * 256;
    float4 accp = {0.f, 0.f, 0.f, 0.f};
    int curg = -1;
    float* pbase = pool + layer * 128 + c4;
    for (int rr = grp; rr < 256; rr += 8) {
        int r = row0 + rr;
        if (r >= NNODES) break;
        float4 v = *(const float4*)&Hin[(size_t)r * 128 + c4];
        v.x = v.x * sc.x + sh.x;
        v.y = v.y * sc.y + sh.y;
        v.z = v.z * sc.z + sh.z;
        v.w = v.w * sc.w + sh.w;
        if (relu) {
            v.x = fmaxf(v.x, 0.f);
            v.y = fmaxf(v.y, 0.f);
            v.z = fmaxf(v.z, 0.f);
            v.w = fmaxf(v.w, 0.f);
        }
        if (Hf32) {
            *(float4*)&Hf32[(size_t)r * 128 + c4] = v;
        } else {
            float vf[4] = {v.x, v.y, v.z, v.w};
            ushort4 hi4, lo4;
            short h;
            h = f2bf(vf[0]); hi4.x = h; lo4.x = f2bf(vf[0] - bf2f(h));
            h = f2bf(vf[1]); hi4.y = h; lo4.y = f2bf(vf[1] - bf2f(h));
            h = f2bf(vf[2]); hi4.z = h; lo4.z = f2bf(vf[2] - bf2f(h));
            h = f2bf(vf[3]); hi4.w = h; lo4.w = f2bf(vf[3] - bf2f(h));
            *(ushort4*)&Hhi[(size_t)r * 128 + c4] = hi4;
            *(ushort4*)&Hlo[(size_t)r * 128 + c4] = lo4;
        }
        int g = batch[r];
        if (g != curg) {
            if (curg >= 0) {
                float* p = pbase + curg * 640;
                atomicAdd(p + 0, accp.x);
                atomicAdd(p + 1, accp.y);
                atomicAdd(p + 2, accp.z);
                atomicAdd(p + 3, accp.w);
            }
            curg = g;
            accp.x = accp.y = accp.z = accp.w = 0.f;
        }
        accp.x += v.x;
        accp.y += v.y;
        accp.z += v.z;
        accp.w += v.w;
    }
    if (curg >= 0) {
        float* p = pbase + curg * 640;
        atomicAdd(p + 0, accp.x);
        atomicAdd(p + 1, accp.y);
        atomicAdd(p + 2, accp.z);
        atomicAdd(p + 3, accp.w);
    }
}

extern "C" void kernel_launch(void* const* d_in, const int* in_sizes, int n_in,
                              void* d_out, int out_size, void* d_ws, size_t ws_size,
                              hipStream_t stream) {
    const int* batch = (const int*)d_in[0];
    const float* x = (const float*)d_in[1];
    const int* edge_index = (const int*)d_in[2];
    const float* edge_attr = (const float*)d_in[3];
    const float* edge_weight = (const float*)d_in[4];
    const float* W_atom = (const float*)d_in[5];
    const float* b_atom = (const float*)d_in[6];
    const float* W_bond = (const float*)d_in[7];
    const float* b_bond = (const float*)d_in[8];
    const float* Wl = (const float*)d_in[9];
    const float* bl = (const float*)d_in[10];
    const float* Wr = (const float*)d_in[11];
    const float* gamma = (const float*)d_in[12];
    const float* beta = (const float*)d_in[13];
    float* out = (float*)d_out;

    // ---- workspace layout ----
    char* ws = (char*)d_ws;
    size_t off = 0;
    auto alloc = [&](size_t bytes) -> void* {
        void* p = ws + off;
        off += (bytes + 255) & ~(size_t)255;
        return p;
    };
    short* Hhi = (short*)alloc((size_t)NNODES * 128 * 2);
    short* Hlo = (short*)alloc((size_t)NNODES * 128 * 2);
    short* Ahi = (short*)alloc((size_t)NNODES * 128 * 2);
    short* Alo = (short*)alloc((size_t)NNODES * 128 * 2);
    float* hB = (float*)alloc((size_t)NNODES * 128 * 4);
    float* eagg = (float*)alloc((size_t)NNODES * 128 * 4);
    int4* epack = (int4*)alloc((size_t)NEDGES * 16);
    int* rowptr = (int*)alloc((size_t)(NNODES + 1) * 4);
    int* cursor = (int*)alloc((size_t)NNODES * 4);
    int* deg = (int*)alloc((size_t)NNODES * 4);
    float* wsum = (float*)alloc((size_t)NNODES * 4);
    float* S = (float*)alloc((size_t)NNODES * 11 * 4);
    float* stat = (float*)alloc(NLAYERS * 256 * 4);
    int* local_excl = (int*)alloc((size_t)NNODES * 4);
    int* part = (int*)alloc(SCAN_BLOCKS * 4);
    int* blockoff = (int*)alloc(SCAN_BLOCKS * 4);
    short* Bf = (short*)alloc((size_t)NLAYERS * 65536 * 2);

    // ---- zero-init accumulation buffers ----
    hipMemsetAsync(out, 0, (size_t)NGRAPHS * 640 * 4, stream);
    hipMemsetAsync(deg, 0, (size_t)NNODES * 4, stream);
    hipMemsetAsync(stat, 0, NLAYERS * 256 * 4, stream);

    // ---- preprocessing ----
    deg_kernel<<<(NEDGES + 255) / 256, 256, 0, stream>>>(edge_index, deg);
    scan1<<<SCAN_BLOCKS, 256, 0, stream>>>(deg, local_excl, part);
    scan2<<<1, 256, 0, stream>>>(part, blockoff, rowptr);
    scan3<<<SCAN_BLOCKS, 256, 0, stream>>>(local_excl, blockoff, rowptr, cursor);
    edge_fill<<<(NEDGES + 255) / 256, 256, 0, stream>>>(edge_index, edge_weight, cursor,
                                                        epack);
    node_S<<<(NNODES + 15) / 16, 256, 0, stream>>>(edge_attr, rowptr, epack, S, wsum);
    bprep<<<(NLAYERS * 32768 + 255) / 256, 256, 0, stream>>>(Wl, Wr, Bf);
    enc_atom<<<(NNODES + 31) / 32, 256, 0, stream>>>(x, W_atom, b_atom, Hhi, Hlo);
    enc_bond<<<(NNODES + 31) / 32, 256, 0, stream>>>(S, W_bond, b_bond, wsum, eagg);

    // ---- layers ----
    for (int i = 0; i < NLAYERS; i++) {
        agg_kernel<<<(NNODES + 7) / 8, 256, 0, stream>>>(Hhi, eagg, rowptr, epack,
                                                         Ahi, Alo);
        layer_gemm<<<(NNODES + 63) / 64, 256, 0, stream>>>(Ahi, Alo, Hhi, Hlo,
                                                           Bf + (size_t)i * 65536,
                                                           bl + i * 128, hB,
                                                           stat + i * 256);
        int last = (i == NLAYERS - 1);
        bn_apply<<<(NNODES + 255) / 256, 256, 0, stream>>>(
            hB, Hhi, Hlo, last ? (out + (size_t)NGRAPHS * 640) : nullptr,
            stat + i * 256, gamma + i * 128, beta + i * 128, batch, out, i,
            last ? 0 : 1);
    }
}